// Round 14
// baseline (118.112 us; speedup 1.0000x reference)
//
#include <hip/hip_runtime.h>

#define NF 16
#define NB 32
#define NN 64
#define EPSV 1e-8f

typedef _Float16 f16x8 __attribute__((ext_vector_type(8)));
typedef _Float16 f16x2 __attribute__((ext_vector_type(2)));
typedef __fp16 fp16x2 __attribute__((ext_vector_type(2)));
typedef float f32x4 __attribute__((ext_vector_type(4)));

// Workspace (float offsets), ping-pong, all overwritten before read each call:
#define SA_OFF    0
#define VA_OFF    32768
#define SB_OFF    131072
#define VB_OFF    163840
#define AGGSA_OFF 262144
#define AGGVA_OFF 524288
#define AGGSB_OFF 1310720
#define AGGVB_OFF 1572864

__device__ __forceinline__ f16x2 cvt_pk(float a, float b) {
    fp16x2 r = __builtin_amdgcn_cvt_pkrtz(a, b);
    return __builtin_bit_cast(f16x2, r);
}

__device__ __forceinline__ f16x8 pack8(f16x2 a, f16x2 b, f16x2 c, f16x2 d) {
    f16x8 r;
    r[0] = a[0]; r[1] = a[1]; r[2] = b[0]; r[3] = b[1];
    r[4] = c[0]; r[5] = c[1]; r[6] = d[0]; r[7] = d[1];
    return r;
}

__device__ __forceinline__ float dot16(const float4* w, const float4* f) {
    float acc = 0.f;
#pragma unroll
    for (int q = 0; q < 4; ++q) {
        acc += w[q].x * f[q].x + w[q].y * f[q].y + w[q].z * f[q].z + w[q].w * f[q].w;
    }
    return acc;
}

// Merged per-layer kernel: [update] + A2/B2 build (LDS) + edge.
// grid 512 = 8 xcd * 4 b * 8 sgrp * 2 fhalf; block owns 8 src nodes, 64 dst.
template <int LAYER>
__global__ __launch_bounds__(256) void k_medge(
        const float* __restrict__ pos,
        const float* __restrict__ z, const float* __restrict__ v,
        const float* __restrict__ w_s_in, const float* __restrict__ w_v_in,
        const float* __restrict__ sws_l, const float* __restrict__ swv_l,
        const float* __restrict__ swv_out, const float* __restrict__ wvo,
        const float* __restrict__ sprev, const float* __restrict__ vprev,
        float* __restrict__ snew, float* __restrict__ vnew,
        const float* __restrict__ aggs_in, const float* __restrict__ aggv_in,
        const float* __restrict__ W2, const float* __restrict__ b2,
        const float* __restrict__ w1, const float* __restrict__ b1,
        float* __restrict__ aggs_out, float* __restrict__ aggv_out,
        float* __restrict__ outp) {
    int blk = blockIdx.x;
    int xcd = blk & 7;
    int t = blk >> 3;                    // 0..63
    int b = xcd * 4 + (t >> 4);
    int rem = t & 15;
    int sgrp = rem >> 1, wfh = rem & 1;
    int tid = threadIdx.x;
    int nbase = b * NN + sgrp * 8;       // this block's 8 src nodes

    __shared__ float pos_sh[NN * 3];
    __shared__ float s_sh[8][16];
    __shared__ float vec_t[3][8][16];    // [d][node][channel]
    __shared__ float aggfull[8][64];
    __shared__ float sigA_sh[8];
    __shared__ int eexp_sh[8];
    __shared__ float wvo2_sh[16];
    __shared__ _Float16 A2sh[8][2048];   // [src][chunk*8 + h7], chunk swizzled
    __shared__ float B2sh[8][64];

    if (tid < NN * 3) pos_sh[tid] = pos[(size_t)b * NN * 3 + tid];

    // ---- coalesced W2 row prefetch: thread t owns row (h = t>>3, i = t&7),
    //      one row per stream m. Consecutive lanes are 64B apart. ----
    int hrow = tid >> 3, i_loc = tid & 7;
    const float* wbase = W2 + (size_t)hrow * 1024 + (wfh * 8 + i_loc) * 16;
    float4 wr[4][4];
#pragma unroll
    for (int m = 0; m < 4; ++m) {
        const float4* p = (const float4*)(wbase + m * 256);
        wr[m][0] = p[0]; wr[m][1] = p[1]; wr[m][2] = p[2]; wr[m][3] = p[3];
    }
    float4 br[4];
    if (tid < 32) {
        const float4* p = (const float4*)(b2 + (tid >> 3) * 256 + (wfh * 8 + (tid & 7)) * 16);
        br[0] = p[0]; br[1] = p[1]; br[2] = p[2]; br[3] = p[3];
    }

    // ---- state phase: init (L0) or update from prev partials (L1,L2) ----
    if (LAYER == 0) {
        for (int it = tid; it < 512; it += 256) {
            int k = it >> 6, ch = it & 63;
            int node = nbase + k;
            if (ch < 16) {
                float val = z[node] * w_s_in[ch];
                s_sh[k][ch] = val;
                if (wfh == 0) snew[node * 16 + ch] = val;
            } else {
                int q = ch - 16, e = q / 3, d = q % 3;
                float val = v[node * 3 + d] * w_v_in[e];
                vec_t[d][k][e] = val;
                if (wfh == 0) vnew[node * 48 + q] = val;
            }
        }
    } else {
        for (int it = tid; it < 512; it += 256) {
            int k = it >> 6, ch = it & 63;
            int node = nbase + k;
            float a = 0.f;
            if (ch < 16) {
#pragma unroll
                for (int p = 0; p < 8; ++p) a += aggs_in[(size_t)p * 32768 + node * 16 + ch];
            } else {
#pragma unroll
                for (int p = 0; p < 8; ++p) a += aggv_in[(size_t)p * 98304 + node * 48 + (ch - 16)];
            }
            aggfull[k][ch] = a;
        }
        __syncthreads();
        for (int it = tid; it < 512; it += 256) {
            int k = it >> 6, ch = it & 63;
            int node = nbase + k;
            if (ch < 16) {
                float acc = 0.f;
#pragma unroll
                for (int c = 0; c < 16; ++c) acc += aggfull[k][c] * sws_l[c * 16 + ch];
                float val = sprev[node * 16 + ch] + fmaxf(acc, 0.f);
                s_sh[k][ch] = val;
                if (LAYER == 1 && wfh == 0) snew[node * 16 + ch] = val;
            } else {
                int q = ch - 16, e = q / 3, d = q % 3;
                float acc = 0.f;
#pragma unroll
                for (int c = 0; c < 16; ++c) acc += aggfull[k][16 + c * 3 + d] * swv_l[c * 16 + e];
                float val = vprev[node * 48 + q] + acc;
                vec_t[d][k][e] = val;
                if (LAYER == 1 && wfh == 0) vnew[node * 48 + q] = val;
            }
        }
    }
    __syncthreads();

    // LAYER 1: write output base term pos + vec_L1 . wvo for this block's nodes
    if (LAYER == 1 && wfh == 0 && tid < 24) {
        int kk = tid / 3, d = tid % 3;
        float acc = 0.f;
#pragma unroll
        for (int e = 0; e < 16; ++e) acc += vec_t[d][kk][e] * wvo[e];
        int loc = (sgrp * 8 + kk) * 3 + d;
        outp[(size_t)b * NN * 3 + loc] = acc + pos_sh[loc];
    }

    // ---- per-node scale exponent: 8 threads/node, shfl reduce ----
    if (tid < 64) {
        int nk = tid >> 3, sub = tid & 7;
        float m = 0.f;
#pragma unroll
        for (int e = 0; e < 8; ++e) {
            int idx = sub * 8 + e;
            float x = (idx < 16) ? s_sh[nk][idx] : vec_t[(idx - 16) >> 4][nk][(idx - 16) & 15];
            m = fmaxf(m, fabsf(x));
        }
        m = fmaxf(m, __shfl_xor(m, 1));
        m = fmaxf(m, __shfl_xor(m, 2));
        m = fmaxf(m, __shfl_xor(m, 4));
        if (sub == 0) {
            unsigned mb = __float_as_uint(m);
            int ex = (int)((mb >> 23) & 0xFF);
            eexp_sh[nk] = ex - 126;
            sigA_sh[nk] = __uint_as_float((unsigned)(253 - ex) << 23);  // 2^(126-ex)
        }
    }
    if (LAYER == 2 && tid >= 64 && tid < 80) {
        int c = tid - 64;
        float acc = 0.f;
#pragma unroll
        for (int e = 0; e < 16; ++e) acc += swv_out[c * 16 + e] * wvo[e];
        wvo2_sh[c] = acc;
    }
    __syncthreads();

    // ---- pre phase: node-outer; state rows via LDS broadcast; W2 in regs ----
    {
        int hq8 = hrow >> 3, h7 = hrow & 7;
#pragma unroll 1
        for (int k2 = 0; k2 < 8; ++k2) {
            float sA = sigA_sh[k2];
            float4 fs[4], fv0[4], fv1[4], fv2[4];
            {
                const float4* ps = (const float4*)&s_sh[k2][0];
                fs[0] = ps[0]; fs[1] = ps[1]; fs[2] = ps[2]; fs[3] = ps[3];
                const float4* p0 = (const float4*)&vec_t[0][k2][0];
                fv0[0] = p0[0]; fv0[1] = p0[1]; fv0[2] = p0[2]; fv0[3] = p0[3];
                const float4* p1 = (const float4*)&vec_t[1][k2][0];
                fv1[0] = p1[0]; fv1[1] = p1[1]; fv1[2] = p1[2]; fv1[3] = p1[3];
                const float4* p2 = (const float4*)&vec_t[2][k2][0];
                fv2[0] = p2[0]; fv2[1] = p2[1]; fv2[2] = p2[2]; fv2[3] = p2[3];
            }
            // emit helper: fg half-local, value scaled+converted, scalar f16 store
            float vals[8];
            vals[0] = dot16(wr[0], fs);     // cc0: Wss . s
            vals[1] = dot16(wr[1], fs);     // cc1: Wsv . s
            vals[2] = dot16(wr[2], fv0);    // cc2..4: Wvs . vec_d
            vals[3] = dot16(wr[2], fv1);
            vals[4] = dot16(wr[2], fv2);
            vals[5] = dot16(wr[3], fv0);    // cc5..7: Wvv . vec_d
            vals[6] = dot16(wr[3], fv1);
            vals[7] = dot16(wr[3], fv2);
#pragma unroll
            for (int cc = 0; cc < 8; ++cc) {
                int fg = i_loc * 8 + cc;
                int mt = fg >> 4, colw = fg & 15;
                int chunk = mt * 64 + hq8 * 16 + ((colw + hq8 * 4) & 15);
                A2sh[k2][chunk * 8 + h7] = (_Float16)(vals[cc] * sA);
            }
            if (tid < 32) {
                int strm_b = tid >> 3, il2 = tid & 7;
                if (strm_b == 0) {
                    B2sh[k2][il2 * 8 + 0] = dot16(br, fs);
                } else if (strm_b == 1) {
                    B2sh[k2][il2 * 8 + 1] = dot16(br, fs);
                } else if (strm_b == 2) {
                    B2sh[k2][il2 * 8 + 2] = dot16(br, fv0);
                    B2sh[k2][il2 * 8 + 3] = dot16(br, fv1);
                    B2sh[k2][il2 * 8 + 4] = dot16(br, fv2);
                } else {
                    B2sh[k2][il2 * 8 + 5] = dot16(br, fv0);
                    B2sh[k2][il2 * 8 + 6] = dot16(br, fv1);
                    B2sh[k2][il2 * 8 + 7] = dot16(br, fv2);
                }
            }
        }
    }
    __syncthreads();

    // ---- edge phase: 4 waves x 16 dst cols, MFMA over 8 srcs from LDS ----
    {
        int wd = tid >> 6;
        int lane = tid & 63;
        int q = lane >> 4, col = lane & 15;
        int dst = wd * 16 + col;
        float qodd = (float)(q & 1);
        float o1 = qodd;

        float pdx = pos_sh[dst * 3 + 0], pdy = pos_sh[dst * 3 + 1], pdz = pos_sh[dst * 3 + 2];
        float w1r[8], b1r[8];
#pragma unroll
        for (int j = 0; j < 8; ++j) { w1r[j] = w1[q * 8 + j]; b1r[j] = b1[q * 8 + j]; }

        int es[8], eblk = -10000;
#pragma unroll
        for (int j = 0; j < 8; ++j) {
            es[j] = eexp_sh[j];
            eblk = es[j] > eblk ? es[j] : eblk;
        }
        float invsb = __uint_as_float((unsigned)(127 + eblk) << 23);  // 2^eblk

        f32x4 acc[4][4];
#pragma unroll
        for (int mt = 0; mt < 4; ++mt)
#pragma unroll
            for (int u = 0; u < 4; ++u) acc[mt][u] = (f32x4){0.f, 0.f, 0.f, 0.f};
        float ms_p[4] = {0.f, 0.f, 0.f, 0.f};
        float mv_p[4][3];
#pragma unroll
        for (int mt = 0; mt < 4; ++mt) { mv_p[mt][0] = 0.f; mv_p[mt][1] = 0.f; mv_p[mt][2] = 0.f; }

        for (int j = 0; j < 8; ++j) {
            int src = sgrp * 8 + j;
            float psx = pos_sh[src * 3 + 0];
            float psy = pos_sh[src * 3 + 1];
            float psz = pos_sh[src * 3 + 2];
            float dx = pdx - psx, dy = pdy - psy, dz = pdz - psz;
            float r = __builtin_amdgcn_sqrtf(dx * dx + dy * dy + dz * dz);
            float inv = __builtin_amdgcn_rcpf(r + EPSV);
            float ux = dx * inv, uy = dy * inv, uz = dz * inv;
            float vmask = (dst == src) ? 0.f : 1.f;

            int dEx = es[j] - eblk;
            float sc2 = (dEx < -120) ? 0.f : __uint_as_float((unsigned)(127 + dEx) << 23);
            float scl = sc2 * vmask;

            f16x2 ux2 = {(_Float16)ux, (_Float16)ux};
            f16x2 uy2 = {(_Float16)uy, (_Float16)uy};
            f16x2 uz2 = {(_Float16)uz, (_Float16)uz};
            f16x2 p0[4], p1[4], p2[4], p3[4];
#pragma unroll
            for (int jp = 0; jp < 4; ++jp) {
                float h0 = fmaxf(fmaf(r, w1r[2 * jp],     b1r[2 * jp]),     0.f) * scl;
                float h1 = fmaxf(fmaf(r, w1r[2 * jp + 1], b1r[2 * jp + 1]), 0.f) * scl;
                p0[jp] = cvt_pk(h0, h1);
                p1[jp] = p0[jp] * ux2;
                p2[jp] = p0[jp] * uy2;
                p3[jp] = p0[jp] * uz2;
            }
            f16x8 bf0 = pack8(p0[0], p0[1], p0[2], p0[3]);
            f16x8 bf1 = pack8(p1[0], p1[1], p1[2], p1[3]);
            f16x8 bf2 = pack8(p2[0], p2[1], p2[2], p2[3]);
            f16x8 bf3 = pack8(p3[0], p3[1], p3[2], p3[3]);

#pragma unroll
            for (int mt = 0; mt < 4; ++mt) {
                f16x8 af = *(const f16x8*)&A2sh[j][(mt * 64 + q * 16 + ((col + q * 4) & 15)) * 8];
                acc[mt][0] = __builtin_amdgcn_mfma_f32_16x16x32_f16(af, bf0, acc[mt][0], 0, 0, 0);
                acc[mt][1] = __builtin_amdgcn_mfma_f32_16x16x32_f16(af, bf1, acc[mt][1], 0, 0, 0);
                acc[mt][2] = __builtin_amdgcn_mfma_f32_16x16x32_f16(af, bf2, acc[mt][2], 0, 0, 0);
                acc[mt][3] = __builtin_amdgcn_mfma_f32_16x16x32_f16(af, bf3, acc[mt][3], 0, 0, 0);
            }

            float s0  = qodd ? uz : 1.f;
            float zx  = qodd ? 0.f : ux;
            float zy  = qodd ? 0.f : uy;
            float exu = qodd ? 1.f : ux;
            float euy = qodd ? 0.f : uy;
            float euz = qodd ? 0.f : uz;
#pragma unroll
            for (int mt = 0; mt < 4; ++mt) {
                float4 bv = *(const float4*)&B2sh[j][mt * 16 + q * 4];
                float t0 = bv.x * vmask, t1 = bv.y * vmask, t2 = bv.z * vmask, t3 = bv.w * vmask;
                ms_p[mt]    += t0 * s0 + t2 * zx + t3 * zy;
                mv_p[mt][0] += t1 * exu;
                mv_p[mt][1] += t1 * euy + t2 * o1;
                mv_p[mt][2] += t1 * euz + t3 * o1;
            }
        }

#pragma unroll
        for (int mt = 0; mt < 4; ++mt) {
            float fs2, fv0, fv1, fv2;
            if ((q & 1) == 0) {
                fs2 = acc[mt][0][0] + acc[mt][1][2] + acc[mt][2][3];
                fv0 = acc[mt][1][1]; fv1 = acc[mt][2][1]; fv2 = acc[mt][3][1];
            } else {
                fs2 = acc[mt][3][0];
                fv0 = acc[mt][0][1]; fv1 = acc[mt][0][2]; fv2 = acc[mt][0][3];
            }
            ms_p[mt]    += fs2 * invsb;
            mv_p[mt][0] += fv0 * invsb;
            mv_p[mt][1] += fv1 * invsb;
            mv_p[mt][2] += fv2 * invsb;
        }

        // single xor-16 reduce (q pairs hold complementary cc-streams of same channel)
#pragma unroll
        for (int mt = 0; mt < 4; ++mt) {
            ms_p[mt]    += __shfl_xor(ms_p[mt], 16, 64);
            mv_p[mt][0] += __shfl_xor(mv_p[mt][0], 16, 64);
            mv_p[mt][1] += __shfl_xor(mv_p[mt][1], 16, 64);
            mv_p[mt][2] += __shfl_xor(mv_p[mt][2], 16, 64);
        }

        if ((q & 1) == 0) {
            int nodeD = b * NN + dst;
            if (LAYER < 2) {
#pragma unroll
                for (int mt = 0; mt < 4; ++mt) {
                    int i2 = (wfh * 4 + mt) * 2 + (q >> 1);
                    aggs_out[(size_t)sgrp * 32768 + nodeD * 16 + i2] = ms_p[mt];
                    float* vp = aggv_out + (size_t)sgrp * 98304 + nodeD * 48 + i2 * 3;
                    vp[0] = mv_p[mt][0]; vp[1] = mv_p[mt][1]; vp[2] = mv_p[mt][2];
                }
            } else {
                float c0 = 0.f, c1 = 0.f, c2 = 0.f;
#pragma unroll
                for (int mt = 0; mt < 4; ++mt) {
                    int i2 = (wfh * 4 + mt) * 2 + (q >> 1);
                    float w2v = wvo2_sh[i2];
                    c0 += mv_p[mt][0] * w2v;
                    c1 += mv_p[mt][1] * w2v;
                    c2 += mv_p[mt][2] * w2v;
                }
                atomicAdd(&outp[(size_t)nodeD * 3 + 0], c0);
                atomicAdd(&outp[(size_t)nodeD * 3 + 1], c1);
                atomicAdd(&outp[(size_t)nodeD * 3 + 2], c2);
            }
        }
    }
}

extern "C" void kernel_launch(void* const* d_in, const int* in_sizes, int n_in,
                              void* d_out, int out_size, void* d_ws, size_t ws_size,
                              hipStream_t stream) {
    const float* pos = (const float*)d_in[0];
    const float* v   = (const float*)d_in[1];
    const float* z   = (const float*)d_in[2];
    const float* w_s_in = (const float*)d_in[3];
    const float* w_v_in = (const float*)d_in[4];
    const float* rw1 = (const float*)d_in[5];
    const float* rb1 = (const float*)d_in[6];
    const float* rw2 = (const float*)d_in[7];
    const float* rb2 = (const float*)d_in[8];
    const float* sws = (const float*)d_in[9];
    const float* swv = (const float*)d_in[10];
    const float* wvo = (const float*)d_in[11];
    float* out = (float*)d_out;

    float* wsf = (float*)d_ws;
    float* sA = wsf + SA_OFF;
    float* vA = wsf + VA_OFF;
    float* sB = wsf + SB_OFF;
    float* vB = wsf + VB_OFF;
    float* aggsA = wsf + AGGSA_OFF;
    float* aggvA = wsf + AGGVA_OFF;
    float* aggsB = wsf + AGGSB_OFF;
    float* aggvB = wsf + AGGVB_OFF;

    // L0: init state -> sA/vA, edge -> aggsA/aggvA
    k_medge<0><<<512, 256, 0, stream>>>(pos, z, v, w_s_in, w_v_in,
                                        sws, swv, swv, wvo, sA, vA, sA, vA,
                                        aggsB, aggvB,
                                        rw2, rb2, rw1, rb1,
                                        aggsA, aggvA, out);
    // L1: update(aggsA)+residual(sA) -> sB/vB (+ out base), edge -> aggsB/aggvB
    k_medge<1><<<512, 256, 0, stream>>>(pos, z, v, w_s_in, w_v_in,
                                        sws, swv, swv, wvo, sA, vA, sB, vB,
                                        aggsA, aggvA,
                                        rw2 + 32768, rb2 + 1024, rw1 + 32, rb1 + 32,
                                        aggsB, aggvB, out);
    // L2: update(aggsB)+residual(sB), edge -> atomicAdd into out (via wvo2)
    k_medge<2><<<512, 256, 0, stream>>>(pos, z, v, w_s_in, w_v_in,
                                        sws + 256, swv + 256, swv + 512, wvo, sB, vB, sA, vA,
                                        aggsB, aggvB,
                                        rw2 + 65536, rb2 + 2048, rw1 + 64, rb1 + 64,
                                        aggsA, aggvA, out);
}

// Round 15
// 85.132 us; speedup vs baseline: 1.3874x; 1.3874x over previous
//
#include <hip/hip_runtime.h>

#define NF 16
#define NB 32
#define NN 64
#define EPSV 1e-8f

typedef _Float16 f16x8 __attribute__((ext_vector_type(8)));
typedef _Float16 f16x2 __attribute__((ext_vector_type(2)));
typedef __fp16 fp16x2 __attribute__((ext_vector_type(2)));
typedef float f32x4 __attribute__((ext_vector_type(4)));

// Workspace (float offsets), ping-pong buffers, all overwritten before read:
//   sA 0        vA 32768     (state after L0 init)
//   sB 131072   vB 163840    (state after L1 update)
//   aggsA 262144  aggvA 524288   (L0 partials; reused for L2)
//   aggsB 1310720 aggvB 1572864  (L1 partials)
#define SA_OFF    0
#define VA_OFF    32768
#define SB_OFF    131072
#define VB_OFF    163840
#define AGGSA_OFF 262144
#define AGGVA_OFF 524288
#define AGGSB_OFF 1310720
#define AGGVB_OFF 1572864

__device__ __forceinline__ f16x2 cvt_pk(float a, float b) {
    fp16x2 r = __builtin_amdgcn_cvt_pkrtz(a, b);
    return __builtin_bit_cast(f16x2, r);
}

__device__ __forceinline__ f16x8 pack8(f16x2 a, f16x2 b, f16x2 c, f16x2 d) {
    f16x8 r;
    r[0] = a[0]; r[1] = a[1]; r[2] = b[0]; r[3] = b[1];
    r[4] = c[0]; r[5] = c[1]; r[6] = d[0]; r[7] = d[1];
    return r;
}

// Merged per-layer kernel: [update from prev partials] + A2/B2 build (LDS) + edge.
// grid 512 = 8 xcd * 4 b * 8 sgrp * 2 fhalf; block owns 8 src nodes, all 64 dst.
template <int LAYER>
__global__ __launch_bounds__(256) void k_medge(
        const float* __restrict__ pos,
        const float* __restrict__ z, const float* __restrict__ v,
        const float* __restrict__ w_s_in, const float* __restrict__ w_v_in,
        const float* __restrict__ sws_l, const float* __restrict__ swv_l,
        const float* __restrict__ sprev, const float* __restrict__ vprev,
        float* __restrict__ snew, float* __restrict__ vnew,
        const float* __restrict__ aggs_in, const float* __restrict__ aggv_in,
        const float* __restrict__ W2, const float* __restrict__ b2,
        const float* __restrict__ w1, const float* __restrict__ b1,
        float* __restrict__ aggs_out, float* __restrict__ aggv_out) {
    int blk = blockIdx.x;
    int xcd = blk & 7;
    int t = blk >> 3;                    // 0..63
    int b = xcd * 4 + (t >> 4);
    int rem = t & 15;
    int sgrp = rem >> 1, wfh = rem & 1;
    int tid = threadIdx.x;
    int nbase = b * NN + sgrp * 8;       // this block's 8 src nodes

    __shared__ float pos_sh[NN * 3];
    __shared__ float s_sh[8][16];
    __shared__ float vec_t[3][8][16];    // [d][node][channel]
    __shared__ float aggfull[8][64];
    __shared__ float sigA_sh[8];
    __shared__ int eexp_sh[8];
    __shared__ _Float16 A2sh[8][2048];   // [src][chunk*8], chunk swizzled
    __shared__ float B2sh[8][64];

    if (tid < NN * 3) pos_sh[tid] = pos[(size_t)b * NN * 3 + tid];

    // ---- state phase: init (L0) or update from prev partials (L1,L2) ----
    if (LAYER == 0) {
        for (int it = tid; it < 512; it += 256) {
            int k = it >> 6, ch = it & 63;
            int node = nbase + k;
            if (ch < 16) {
                float val = z[node] * w_s_in[ch];
                s_sh[k][ch] = val;
                if (wfh == 0) snew[node * 16 + ch] = val;
            } else {
                int q = ch - 16, e = q / 3, d = q % 3;
                float val = v[node * 3 + d] * w_v_in[e];
                vec_t[d][k][e] = val;
                if (wfh == 0) vnew[node * 48 + q] = val;
            }
        }
    } else {
        for (int it = tid; it < 512; it += 256) {
            int k = it >> 6, ch = it & 63;
            int node = nbase + k;
            float a = 0.f;
            if (ch < 16) {
#pragma unroll
                for (int p = 0; p < 8; ++p) a += aggs_in[(size_t)p * 32768 + node * 16 + ch];
            } else {
#pragma unroll
                for (int p = 0; p < 8; ++p) a += aggv_in[(size_t)p * 98304 + node * 48 + (ch - 16)];
            }
            aggfull[k][ch] = a;
        }
        __syncthreads();
        for (int it = tid; it < 512; it += 256) {
            int k = it >> 6, ch = it & 63;
            int node = nbase + k;
            if (ch < 16) {
                float acc = 0.f;
#pragma unroll
                for (int c = 0; c < 16; ++c) acc += aggfull[k][c] * sws_l[c * 16 + ch];
                float val = sprev[node * 16 + ch] + fmaxf(acc, 0.f);
                s_sh[k][ch] = val;
                if (LAYER == 1 && wfh == 0) snew[node * 16 + ch] = val;
            } else {
                int q = ch - 16, e = q / 3, d = q % 3;
                float acc = 0.f;
#pragma unroll
                for (int c = 0; c < 16; ++c) acc += aggfull[k][16 + c * 3 + d] * swv_l[c * 16 + e];
                float val = vprev[node * 48 + q] + acc;
                vec_t[d][k][e] = val;
                if (LAYER == 1 && wfh == 0) vnew[node * 48 + q] = val;
            }
        }
    }
    __syncthreads();

    // ---- per-node scale exponent (block-local) ----
    if (tid < 8) {
        float m = 0.f;
#pragma unroll
        for (int j = 0; j < 16; ++j) m = fmaxf(m, fabsf(s_sh[tid][j]));
#pragma unroll
        for (int d = 0; d < 3; ++d)
#pragma unroll
            for (int e = 0; e < 16; ++e) m = fmaxf(m, fabsf(vec_t[d][tid][e]));
        unsigned mb = __float_as_uint(m);
        int ex = (int)((mb >> 23) & 0xFF);
        eexp_sh[tid] = ex - 126;
        sigA_sh[tid] = __uint_as_float((unsigned)(253 - ex) << 23);  // 2^(126-ex)
    }
    __syncthreads();

    // ---- pre phase: build this block's A2/B2 half into LDS ----
    {
        int fh = tid >> 2, hq8 = tid & 3;      // fh 0..63 within half
        int fg = wfh * 64 + fh;
        int i = fg >> 3, cc = fg & 7;
        int strm = (cc == 0) ? 0 : (cc == 1) ? 1 : (cc <= 4) ? 2 : 3;
        int dd = (cc <= 1) ? 0 : (cc <= 4 ? cc - 2 : cc - 5);
        const float* wp = W2 + (size_t)(hq8 * 8) * 1024 + strm * 256 + i * 16;
        int mt = fh >> 4, colw = fh & 15;
        int chunk = mt * 64 + hq8 * 16 + ((colw + hq8 * 4) & 15);  // bank swizzle

        float bw[16];
        if (hq8 == 0) {
            const float* bp = b2 + strm * 256 + i * 16;
#pragma unroll
            for (int qq = 0; qq < 4; ++qq) {
                float4 x = *(const float4*)(bp + qq * 4);
                bw[qq * 4 + 0] = x.x; bw[qq * 4 + 1] = x.y;
                bw[qq * 4 + 2] = x.z; bw[qq * 4 + 3] = x.w;
            }
        }

        for (int pass = 0; pass < 2; ++pass) {
            int kb = pass * 4;
            float ft[4][16];
#pragma unroll
            for (int k2 = 0; k2 < 4; ++k2) {
                const float* srcp = (strm <= 1) ? &s_sh[kb + k2][0] : &vec_t[dd][kb + k2][0];
#pragma unroll
                for (int qq = 0; qq < 4; ++qq) {
                    float4 x = *(const float4*)(srcp + qq * 4);
                    ft[k2][qq * 4 + 0] = x.x; ft[k2][qq * 4 + 1] = x.y;
                    ft[k2][qq * 4 + 2] = x.z; ft[k2][qq * 4 + 3] = x.w;
                }
            }
            float outv[4][8];
#pragma unroll
            for (int k2 = 0; k2 < 4; ++k2)
#pragma unroll
                for (int h8 = 0; h8 < 8; ++h8) outv[k2][h8] = 0.f;
#pragma unroll
            for (int h8 = 0; h8 < 8; ++h8) {
                const float4* w4 = (const float4*)(wp + h8 * 1024);
                float4 a0 = w4[0], a1 = w4[1], a2 = w4[2], a3 = w4[3];
                float w[16] = {a0.x,a0.y,a0.z,a0.w, a1.x,a1.y,a1.z,a1.w,
                               a2.x,a2.y,a2.z,a2.w, a3.x,a3.y,a3.z,a3.w};
#pragma unroll
                for (int k2 = 0; k2 < 4; ++k2) {
                    float acc = 0.f;
#pragma unroll
                    for (int j = 0; j < 16; ++j) acc += w[j] * ft[k2][j];
                    outv[k2][h8] = acc;
                }
            }
#pragma unroll
            for (int k2 = 0; k2 < 4; ++k2) {
                float sA = sigA_sh[kb + k2];
                f16x8 st;
#pragma unroll
                for (int h8 = 0; h8 < 8; ++h8) st[h8] = (_Float16)(outv[k2][h8] * sA);
                *(f16x8*)&A2sh[kb + k2][chunk * 8] = st;
            }
            if (hq8 == 0) {
#pragma unroll
                for (int k2 = 0; k2 < 4; ++k2) {
                    float acc = 0.f;
#pragma unroll
                    for (int j = 0; j < 16; ++j) acc += bw[j] * ft[k2][j];
                    B2sh[kb + k2][fh] = acc;   // unscaled
                }
            }
        }
    }
    __syncthreads();

    // ---- edge phase: 4 waves x 16 dst cols, MFMA over 8 srcs from LDS ----
    {
        int wd = tid >> 6;
        int lane = tid & 63;
        int q = lane >> 4, col = lane & 15;
        int dst = wd * 16 + col;
        float qodd = (float)(q & 1);
        float o1 = qodd;

        float pdx = pos_sh[dst * 3 + 0], pdy = pos_sh[dst * 3 + 1], pdz = pos_sh[dst * 3 + 2];
        float w1r[8], b1r[8];
#pragma unroll
        for (int j = 0; j < 8; ++j) { w1r[j] = w1[q * 8 + j]; b1r[j] = b1[q * 8 + j]; }

        int es[8], eblk = -10000;
#pragma unroll
        for (int j = 0; j < 8; ++j) {
            es[j] = eexp_sh[j];
            eblk = es[j] > eblk ? es[j] : eblk;
        }
        float invsb = __uint_as_float((unsigned)(127 + eblk) << 23);  // 2^eblk

        f32x4 acc[4][4];
#pragma unroll
        for (int mt = 0; mt < 4; ++mt)
#pragma unroll
            for (int u = 0; u < 4; ++u) acc[mt][u] = (f32x4){0.f, 0.f, 0.f, 0.f};
        float ms_p[4] = {0.f, 0.f, 0.f, 0.f};
        float mv_p[4][3];
#pragma unroll
        for (int mt = 0; mt < 4; ++mt) { mv_p[mt][0] = 0.f; mv_p[mt][1] = 0.f; mv_p[mt][2] = 0.f; }

        for (int j = 0; j < 8; ++j) {
            int src = sgrp * 8 + j;
            float psx = pos_sh[src * 3 + 0];
            float psy = pos_sh[src * 3 + 1];
            float psz = pos_sh[src * 3 + 2];
            float dx = pdx - psx, dy = pdy - psy, dz = pdz - psz;
            float r = __builtin_amdgcn_sqrtf(dx * dx + dy * dy + dz * dz);
            float inv = __builtin_amdgcn_rcpf(r + EPSV);
            float ux = dx * inv, uy = dy * inv, uz = dz * inv;
            float vmask = (dst == src) ? 0.f : 1.f;

            int dEx = es[j] - eblk;
            float sc2 = (dEx < -120) ? 0.f : __uint_as_float((unsigned)(127 + dEx) << 23);
            float scl = sc2 * vmask;

            f16x2 ux2 = {(_Float16)ux, (_Float16)ux};
            f16x2 uy2 = {(_Float16)uy, (_Float16)uy};
            f16x2 uz2 = {(_Float16)uz, (_Float16)uz};
            f16x2 p0[4], p1[4], p2[4], p3[4];
#pragma unroll
            for (int jp = 0; jp < 4; ++jp) {
                float h0 = fmaxf(fmaf(r, w1r[2 * jp],     b1r[2 * jp]),     0.f) * scl;
                float h1 = fmaxf(fmaf(r, w1r[2 * jp + 1], b1r[2 * jp + 1]), 0.f) * scl;
                p0[jp] = cvt_pk(h0, h1);
                p1[jp] = p0[jp] * ux2;
                p2[jp] = p0[jp] * uy2;
                p3[jp] = p0[jp] * uz2;
            }
            f16x8 bf0 = pack8(p0[0], p0[1], p0[2], p0[3]);
            f16x8 bf1 = pack8(p1[0], p1[1], p1[2], p1[3]);
            f16x8 bf2 = pack8(p2[0], p2[1], p2[2], p2[3]);
            f16x8 bf3 = pack8(p3[0], p3[1], p3[2], p3[3]);

#pragma unroll
            for (int mt = 0; mt < 4; ++mt) {
                f16x8 af = *(const f16x8*)&A2sh[j][(mt * 64 + q * 16 + ((col + q * 4) & 15)) * 8];
                acc[mt][0] = __builtin_amdgcn_mfma_f32_16x16x32_f16(af, bf0, acc[mt][0], 0, 0, 0);
                acc[mt][1] = __builtin_amdgcn_mfma_f32_16x16x32_f16(af, bf1, acc[mt][1], 0, 0, 0);
                acc[mt][2] = __builtin_amdgcn_mfma_f32_16x16x32_f16(af, bf2, acc[mt][2], 0, 0, 0);
                acc[mt][3] = __builtin_amdgcn_mfma_f32_16x16x32_f16(af, bf3, acc[mt][3], 0, 0, 0);
            }

            float s0  = qodd ? uz : 1.f;
            float zx  = qodd ? 0.f : ux;
            float zy  = qodd ? 0.f : uy;
            float exu = qodd ? 1.f : ux;
            float euy = qodd ? 0.f : uy;
            float euz = qodd ? 0.f : uz;
#pragma unroll
            for (int mt = 0; mt < 4; ++mt) {
                float4 bv = *(const float4*)&B2sh[j][mt * 16 + q * 4];
                float t0 = bv.x * vmask, t1 = bv.y * vmask, t2 = bv.z * vmask, t3 = bv.w * vmask;
                ms_p[mt]    += t0 * s0 + t2 * zx + t3 * zy;
                mv_p[mt][0] += t1 * exu;
                mv_p[mt][1] += t1 * euy + t2 * o1;
                mv_p[mt][2] += t1 * euz + t3 * o1;
            }
        }

#pragma unroll
        for (int mt = 0; mt < 4; ++mt) {
            float fs, fv0, fv1, fv2;
            if ((q & 1) == 0) {
                fs  = acc[mt][0][0] + acc[mt][1][2] + acc[mt][2][3];
                fv0 = acc[mt][1][1]; fv1 = acc[mt][2][1]; fv2 = acc[mt][3][1];
            } else {
                fs  = acc[mt][3][0];
                fv0 = acc[mt][0][1]; fv1 = acc[mt][0][2]; fv2 = acc[mt][0][3];
            }
            ms_p[mt]    += fs  * invsb;
            mv_p[mt][0] += fv0 * invsb;
            mv_p[mt][1] += fv1 * invsb;
            mv_p[mt][2] += fv2 * invsb;
        }

        // single xor-16 reduce (q pairs hold complementary cc-streams of same channel)
#pragma unroll
        for (int mt = 0; mt < 4; ++mt) {
            ms_p[mt]    += __shfl_xor(ms_p[mt], 16, 64);
            mv_p[mt][0] += __shfl_xor(mv_p[mt][0], 16, 64);
            mv_p[mt][1] += __shfl_xor(mv_p[mt][1], 16, 64);
            mv_p[mt][2] += __shfl_xor(mv_p[mt][2], 16, 64);
        }

        if ((q & 1) == 0) {
            int nodeD = b * NN + dst;
#pragma unroll
            for (int mt = 0; mt < 4; ++mt) {
                int i2 = (wfh * 4 + mt) * 2 + (q >> 1);
                aggs_out[(size_t)sgrp * 32768 + nodeD * 16 + i2] = ms_p[mt];
                float* vp = aggv_out + (size_t)sgrp * 98304 + nodeD * 48 + i2 * 3;
                vp[0] = mv_p[mt][0]; vp[1] = mv_p[mt][1]; vp[2] = mv_p[mt][2];
            }
        }
    }
}

__global__ __launch_bounds__(256) void k_out(
        const float* __restrict__ aggv, const float* __restrict__ wv,
        const float* __restrict__ wvo, const float* __restrict__ vec,
        const float* __restrict__ pos, float* __restrict__ out) {
    int node0 = blockIdx.x * 4;
    int tid = threadIdx.x;
    int k = tid >> 6, t = tid & 63;
    int node = node0 + k;
    __shared__ float avh[4][48];
    __shared__ float vn[4][48];
    if (t < 48) {
        float a = 0.f;
#pragma unroll
        for (int p = 0; p < 8; ++p) a += aggv[(size_t)p * 98304 + node * 48 + t];
        avh[k][t] = a;
    }
    __syncthreads();
    if (t < 48) {
        int e = t / 3, d = t % 3;
        float acc = 0.f;
#pragma unroll
        for (int c = 0; c < 16; ++c) acc += avh[k][c * 3 + d] * wv[c * 16 + e];
        vn[k][t] = (vec[node * 48 + t] + acc) * wvo[e];
    }
    __syncthreads();
    if (t < 3) {
        float acc = 0.f;
#pragma unroll
        for (int e = 0; e < 16; ++e) acc += vn[k][e * 3 + t];
        out[node * 3 + t] = acc + pos[node * 3 + t];
    }
}

extern "C" void kernel_launch(void* const* d_in, const int* in_sizes, int n_in,
                              void* d_out, int out_size, void* d_ws, size_t ws_size,
                              hipStream_t stream) {
    const float* pos = (const float*)d_in[0];
    const float* v   = (const float*)d_in[1];
    const float* z   = (const float*)d_in[2];
    const float* w_s_in = (const float*)d_in[3];
    const float* w_v_in = (const float*)d_in[4];
    const float* rw1 = (const float*)d_in[5];
    const float* rb1 = (const float*)d_in[6];
    const float* rw2 = (const float*)d_in[7];
    const float* rb2 = (const float*)d_in[8];
    const float* sws = (const float*)d_in[9];
    const float* swv = (const float*)d_in[10];
    const float* wvo = (const float*)d_in[11];
    float* out = (float*)d_out;

    float* wsf = (float*)d_ws;
    float* sA = wsf + SA_OFF;
    float* vA = wsf + VA_OFF;
    float* sB = wsf + SB_OFF;
    float* vB = wsf + VB_OFF;
    float* aggsA = wsf + AGGSA_OFF;
    float* aggvA = wsf + AGGVA_OFF;
    float* aggsB = wsf + AGGSB_OFF;
    float* aggvB = wsf + AGGVB_OFF;

    // L0: init state -> sA/vA, edge -> aggsA/aggvA
    k_medge<0><<<512, 256, 0, stream>>>(pos, z, v, w_s_in, w_v_in,
                                        sws, swv, sA, vA, sA, vA,
                                        aggsB, aggvB,
                                        rw2, rb2, rw1, rb1,
                                        aggsA, aggvA);
    // L1: update(aggsA)+residual(sA) -> sB/vB, edge -> aggsB/aggvB
    k_medge<1><<<512, 256, 0, stream>>>(pos, z, v, w_s_in, w_v_in,
                                        sws, swv, sA, vA, sB, vB,
                                        aggsA, aggvA,
                                        rw2 + 32768, rb2 + 1024, rw1 + 32, rb1 + 32,
                                        aggsB, aggvB);
    // L2: update(aggsB)+residual(sB) (no state write), edge -> aggsA/aggvA
    k_medge<2><<<512, 256, 0, stream>>>(pos, z, v, w_s_in, w_v_in,
                                        sws + 256, swv + 256, sB, vB, sA, vA,
                                        aggsB, aggvB,
                                        rw2 + 65536, rb2 + 2048, rw1 + 64, rb1 + 64,
                                        aggsA, aggvA);
    // out: vec_L1 (vB) + L2 partials (aggvA)
    k_out<<<512, 256, 0, stream>>>(aggvA, swv + 512, wvo, vB, pos, out);
}

// Round 16
// 76.376 us; speedup vs baseline: 1.5464x; 1.1146x over previous
//
#include <hip/hip_runtime.h>

#define NF 16
#define NB 32
#define NN 64
#define EPSV 1e-8f

typedef _Float16 f16x8 __attribute__((ext_vector_type(8)));
typedef _Float16 f16x2 __attribute__((ext_vector_type(2)));
typedef __fp16 fp16x2 __attribute__((ext_vector_type(2)));
typedef float f32x4 __attribute__((ext_vector_type(4)));

// Workspace (float offsets), ping-pong buffers, all overwritten before read:
#define SA_OFF    0
#define VA_OFF    32768
#define SB_OFF    131072
#define VB_OFF    163840
#define AGGSA_OFF 262144
#define AGGVA_OFF 524288
#define AGGSB_OFF 1310720
#define AGGVB_OFF 1572864

__device__ __forceinline__ f16x2 cvt_pk(float a, float b) {
    fp16x2 r = __builtin_amdgcn_cvt_pkrtz(a, b);
    return __builtin_bit_cast(f16x2, r);
}

__device__ __forceinline__ f16x8 pack8(f16x2 a, f16x2 b, f16x2 c, f16x2 d) {
    f16x8 r;
    r[0] = a[0]; r[1] = a[1]; r[2] = b[0]; r[3] = b[1];
    r[4] = c[0]; r[5] = c[1]; r[6] = d[0]; r[7] = d[1];
    return r;
}

// Merged per-layer kernel: [update from prev partials] + A2/B2 build (LDS) + edge.
// grid 512 = 8 xcd * 4 b * 8 sgrp * 2 fhalf; block owns 8 src nodes, all 64 dst.
// Grid-limited to 2 waves/SIMD, so VGPR budget to 256 is free: W2 half-tile is
// preloaded ONCE into registers at kernel top (latency overlaps state phase).
template <int LAYER>
__global__ __launch_bounds__(256, 2) void k_medge(
        const float* __restrict__ pos,
        const float* __restrict__ z, const float* __restrict__ v,
        const float* __restrict__ w_s_in, const float* __restrict__ w_v_in,
        const float* __restrict__ sws_l, const float* __restrict__ swv_l,
        const float* __restrict__ sprev, const float* __restrict__ vprev,
        float* __restrict__ snew, float* __restrict__ vnew,
        const float* __restrict__ aggs_in, const float* __restrict__ aggv_in,
        const float* __restrict__ W2, const float* __restrict__ b2,
        const float* __restrict__ w1, const float* __restrict__ b1,
        float* __restrict__ aggs_out, float* __restrict__ aggv_out) {
    int blk = blockIdx.x;
    int xcd = blk & 7;
    int t = blk >> 3;                    // 0..63
    int b = xcd * 4 + (t >> 4);
    int rem = t & 15;
    int sgrp = rem >> 1, wfh = rem & 1;
    int tid = threadIdx.x;
    int nbase = b * NN + sgrp * 8;       // this block's 8 src nodes

    __shared__ float pos_sh[NN * 3];
    __shared__ float s_sh[8][16];
    __shared__ float vec_t[3][8][16];    // [d][node][channel]
    __shared__ float aggfull[8][64];
    __shared__ float sigA_sh[8];
    __shared__ int eexp_sh[8];
    __shared__ _Float16 A2sh[8][2048];   // [src][chunk*8], chunk swizzled
    __shared__ float B2sh[8][64];

    if (tid < NN * 3) pos_sh[tid] = pos[(size_t)b * NN * 3 + tid];

    // ---- W2/b2 preload (once, hoisted): thread owns row-octet (hq8) of one
    //      stream for output row i — same addressing as the original pre phase.
    int fh_p = tid >> 2, hq8_p = tid & 3;   // fh 0..63 within half, h-octet
    int fg_p = wfh * 64 + fh_p;
    int i_p = fg_p >> 3, cc_p = fg_p & 7;
    int strm_p = (cc_p == 0) ? 0 : (cc_p == 1) ? 1 : (cc_p <= 4) ? 2 : 3;
    int dd_p = (cc_p <= 1) ? 0 : (cc_p <= 4 ? cc_p - 2 : cc_p - 5);
    const float* wp_p = W2 + (size_t)(hq8_p * 8) * 1024 + strm_p * 256 + i_p * 16;
    float4 wr_all[8][4];
#pragma unroll
    for (int h8 = 0; h8 < 8; ++h8) {
        const float4* w4 = (const float4*)(wp_p + h8 * 1024);
        wr_all[h8][0] = w4[0]; wr_all[h8][1] = w4[1];
        wr_all[h8][2] = w4[2]; wr_all[h8][3] = w4[3];
    }
    float4 bw_p[4];
    if (hq8_p == 0) {
        const float4* bp = (const float4*)(b2 + strm_p * 256 + i_p * 16);
        bw_p[0] = bp[0]; bw_p[1] = bp[1]; bw_p[2] = bp[2]; bw_p[3] = bp[3];
    }

    // ---- state phase: init (L0) or update from prev partials (L1,L2) ----
    if (LAYER == 0) {
        for (int it = tid; it < 512; it += 256) {
            int k = it >> 6, ch = it & 63;
            int node = nbase + k;
            if (ch < 16) {
                float val = z[node] * w_s_in[ch];
                s_sh[k][ch] = val;
                if (wfh == 0) snew[node * 16 + ch] = val;
            } else {
                int q = ch - 16, e = q / 3, d = q % 3;
                float val = v[node * 3 + d] * w_v_in[e];
                vec_t[d][k][e] = val;
                if (wfh == 0) vnew[node * 48 + q] = val;
            }
        }
    } else {
        for (int it = tid; it < 512; it += 256) {
            int k = it >> 6, ch = it & 63;
            int node = nbase + k;
            float a = 0.f;
            if (ch < 16) {
#pragma unroll
                for (int p = 0; p < 8; ++p) a += aggs_in[(size_t)p * 32768 + node * 16 + ch];
            } else {
#pragma unroll
                for (int p = 0; p < 8; ++p) a += aggv_in[(size_t)p * 98304 + node * 48 + (ch - 16)];
            }
            aggfull[k][ch] = a;
        }
        __syncthreads();
        for (int it = tid; it < 512; it += 256) {
            int k = it >> 6, ch = it & 63;
            int node = nbase + k;
            if (ch < 16) {
                float acc = 0.f;
#pragma unroll
                for (int c = 0; c < 16; ++c) acc += aggfull[k][c] * sws_l[c * 16 + ch];
                float val = sprev[node * 16 + ch] + fmaxf(acc, 0.f);
                s_sh[k][ch] = val;
                if (LAYER == 1 && wfh == 0) snew[node * 16 + ch] = val;
            } else {
                int q = ch - 16, e = q / 3, d = q % 3;
                float acc = 0.f;
#pragma unroll
                for (int c = 0; c < 16; ++c) acc += aggfull[k][16 + c * 3 + d] * swv_l[c * 16 + e];
                float val = vprev[node * 48 + q] + acc;
                vec_t[d][k][e] = val;
                if (LAYER == 1 && wfh == 0) vnew[node * 48 + q] = val;
            }
        }
    }
    __syncthreads();

    // ---- per-node scale exponent (block-local) ----
    if (tid < 8) {
        float m = 0.f;
#pragma unroll
        for (int j = 0; j < 16; ++j) m = fmaxf(m, fabsf(s_sh[tid][j]));
#pragma unroll
        for (int d = 0; d < 3; ++d)
#pragma unroll
            for (int e = 0; e < 16; ++e) m = fmaxf(m, fabsf(vec_t[d][tid][e]));
        unsigned mb = __float_as_uint(m);
        int ex = (int)((mb >> 23) & 0xFF);
        eexp_sh[tid] = ex - 126;
        sigA_sh[tid] = __uint_as_float((unsigned)(253 - ex) << 23);  // 2^(126-ex)
    }
    __syncthreads();

    // ---- pre phase: single k2 sweep; W2 already in registers; same stores ----
    {
        int mt = fh_p >> 4, colw = fh_p & 15;
        int chunk = mt * 64 + hq8_p * 16 + ((colw + hq8_p * 4) & 15);  // bank swizzle
#pragma unroll
        for (int k2 = 0; k2 < 8; ++k2) {
            const float* srcp = (strm_p <= 1) ? &s_sh[k2][0] : &vec_t[dd_p][k2][0];
            const float4* f4 = (const float4*)srcp;
            float4 f0 = f4[0], f1 = f4[1], f2 = f4[2], f3 = f4[3];
            float sA = sigA_sh[k2];
            f16x8 st;
#pragma unroll
            for (int h8 = 0; h8 < 8; ++h8) {
                float4 a0 = wr_all[h8][0], a1 = wr_all[h8][1];
                float4 a2 = wr_all[h8][2], a3 = wr_all[h8][3];
                float acc = a0.x * f0.x + a0.y * f0.y + a0.z * f0.z + a0.w * f0.w
                          + a1.x * f1.x + a1.y * f1.y + a1.z * f1.z + a1.w * f1.w
                          + a2.x * f2.x + a2.y * f2.y + a2.z * f2.z + a2.w * f2.w
                          + a3.x * f3.x + a3.y * f3.y + a3.z * f3.z + a3.w * f3.w;
                st[h8] = (_Float16)(acc * sA);
            }
            *(f16x8*)&A2sh[k2][chunk * 8] = st;
            if (hq8_p == 0) {
                float accb = bw_p[0].x * f0.x + bw_p[0].y * f0.y + bw_p[0].z * f0.z + bw_p[0].w * f0.w
                           + bw_p[1].x * f1.x + bw_p[1].y * f1.y + bw_p[1].z * f1.z + bw_p[1].w * f1.w
                           + bw_p[2].x * f2.x + bw_p[2].y * f2.y + bw_p[2].z * f2.z + bw_p[2].w * f2.w
                           + bw_p[3].x * f3.x + bw_p[3].y * f3.y + bw_p[3].z * f3.z + bw_p[3].w * f3.w;
                B2sh[k2][fh_p] = accb;   // unscaled
            }
        }
    }
    __syncthreads();

    // ---- edge phase: 4 waves x 16 dst cols, MFMA over 8 srcs from LDS ----
    {
        int wd = tid >> 6;
        int lane = tid & 63;
        int q = lane >> 4, col = lane & 15;
        int dst = wd * 16 + col;
        float qodd = (float)(q & 1);
        float o1 = qodd;

        float pdx = pos_sh[dst * 3 + 0], pdy = pos_sh[dst * 3 + 1], pdz = pos_sh[dst * 3 + 2];
        float w1r[8], b1r[8];
#pragma unroll
        for (int j = 0; j < 8; ++j) { w1r[j] = w1[q * 8 + j]; b1r[j] = b1[q * 8 + j]; }

        int es[8], eblk = -10000;
#pragma unroll
        for (int j = 0; j < 8; ++j) {
            es[j] = eexp_sh[j];
            eblk = es[j] > eblk ? es[j] : eblk;
        }
        float invsb = __uint_as_float((unsigned)(127 + eblk) << 23);  // 2^eblk

        f32x4 acc[4][4];
#pragma unroll
        for (int mt = 0; mt < 4; ++mt)
#pragma unroll
            for (int u = 0; u < 4; ++u) acc[mt][u] = (f32x4){0.f, 0.f, 0.f, 0.f};
        float ms_p[4] = {0.f, 0.f, 0.f, 0.f};
        float mv_p[4][3];
#pragma unroll
        for (int mt = 0; mt < 4; ++mt) { mv_p[mt][0] = 0.f; mv_p[mt][1] = 0.f; mv_p[mt][2] = 0.f; }

        for (int j = 0; j < 8; ++j) {
            int src = sgrp * 8 + j;
            float psx = pos_sh[src * 3 + 0];
            float psy = pos_sh[src * 3 + 1];
            float psz = pos_sh[src * 3 + 2];
            float dx = pdx - psx, dy = pdy - psy, dz = pdz - psz;
            float r = __builtin_amdgcn_sqrtf(dx * dx + dy * dy + dz * dz);
            float inv = __builtin_amdgcn_rcpf(r + EPSV);
            float ux = dx * inv, uy = dy * inv, uz = dz * inv;
            float vmask = (dst == src) ? 0.f : 1.f;

            int dEx = es[j] - eblk;
            float sc2 = (dEx < -120) ? 0.f : __uint_as_float((unsigned)(127 + dEx) << 23);
            float scl = sc2 * vmask;

            f16x2 ux2 = {(_Float16)ux, (_Float16)ux};
            f16x2 uy2 = {(_Float16)uy, (_Float16)uy};
            f16x2 uz2 = {(_Float16)uz, (_Float16)uz};
            f16x2 p0[4], p1[4], p2[4], p3[4];
#pragma unroll
            for (int jp = 0; jp < 4; ++jp) {
                float h0 = fmaxf(fmaf(r, w1r[2 * jp],     b1r[2 * jp]),     0.f) * scl;
                float h1 = fmaxf(fmaf(r, w1r[2 * jp + 1], b1r[2 * jp + 1]), 0.f) * scl;
                p0[jp] = cvt_pk(h0, h1);
                p1[jp] = p0[jp] * ux2;
                p2[jp] = p0[jp] * uy2;
                p3[jp] = p0[jp] * uz2;
            }
            f16x8 bf0 = pack8(p0[0], p0[1], p0[2], p0[3]);
            f16x8 bf1 = pack8(p1[0], p1[1], p1[2], p1[3]);
            f16x8 bf2 = pack8(p2[0], p2[1], p2[2], p2[3]);
            f16x8 bf3 = pack8(p3[0], p3[1], p3[2], p3[3]);

#pragma unroll
            for (int mt = 0; mt < 4; ++mt) {
                f16x8 af = *(const f16x8*)&A2sh[j][(mt * 64 + q * 16 + ((col + q * 4) & 15)) * 8];
                acc[mt][0] = __builtin_amdgcn_mfma_f32_16x16x32_f16(af, bf0, acc[mt][0], 0, 0, 0);
                acc[mt][1] = __builtin_amdgcn_mfma_f32_16x16x32_f16(af, bf1, acc[mt][1], 0, 0, 0);
                acc[mt][2] = __builtin_amdgcn_mfma_f32_16x16x32_f16(af, bf2, acc[mt][2], 0, 0, 0);
                acc[mt][3] = __builtin_amdgcn_mfma_f32_16x16x32_f16(af, bf3, acc[mt][3], 0, 0, 0);
            }

            float s0  = qodd ? uz : 1.f;
            float zx  = qodd ? 0.f : ux;
            float zy  = qodd ? 0.f : uy;
            float exu = qodd ? 1.f : ux;
            float euy = qodd ? 0.f : uy;
            float euz = qodd ? 0.f : uz;
#pragma unroll
            for (int mt = 0; mt < 4; ++mt) {
                float4 bv = *(const float4*)&B2sh[j][mt * 16 + q * 4];
                float t0 = bv.x * vmask, t1 = bv.y * vmask, t2 = bv.z * vmask, t3 = bv.w * vmask;
                ms_p[mt]    += t0 * s0 + t2 * zx + t3 * zy;
                mv_p[mt][0] += t1 * exu;
                mv_p[mt][1] += t1 * euy + t2 * o1;
                mv_p[mt][2] += t1 * euz + t3 * o1;
            }
        }

#pragma unroll
        for (int mt = 0; mt < 4; ++mt) {
            float fs, fv0, fv1, fv2;
            if ((q & 1) == 0) {
                fs  = acc[mt][0][0] + acc[mt][1][2] + acc[mt][2][3];
                fv0 = acc[mt][1][1]; fv1 = acc[mt][2][1]; fv2 = acc[mt][3][1];
            } else {
                fs  = acc[mt][3][0];
                fv0 = acc[mt][0][1]; fv1 = acc[mt][0][2]; fv2 = acc[mt][0][3];
            }
            ms_p[mt]    += fs  * invsb;
            mv_p[mt][0] += fv0 * invsb;
            mv_p[mt][1] += fv1 * invsb;
            mv_p[mt][2] += fv2 * invsb;
        }

        // single xor-16 reduce (q pairs hold complementary cc-streams of same channel)
#pragma unroll
        for (int mt = 0; mt < 4; ++mt) {
            ms_p[mt]    += __shfl_xor(ms_p[mt], 16, 64);
            mv_p[mt][0] += __shfl_xor(mv_p[mt][0], 16, 64);
            mv_p[mt][1] += __shfl_xor(mv_p[mt][1], 16, 64);
            mv_p[mt][2] += __shfl_xor(mv_p[mt][2], 16, 64);
        }

        if ((q & 1) == 0) {
            int nodeD = b * NN + dst;
#pragma unroll
            for (int mt = 0; mt < 4; ++mt) {
                int i2 = (wfh * 4 + mt) * 2 + (q >> 1);
                aggs_out[(size_t)sgrp * 32768 + nodeD * 16 + i2] = ms_p[mt];
                float* vp = aggv_out + (size_t)sgrp * 98304 + nodeD * 48 + i2 * 3;
                vp[0] = mv_p[mt][0]; vp[1] = mv_p[mt][1]; vp[2] = mv_p[mt][2];
            }
        }
    }
}

__global__ __launch_bounds__(256) void k_out(
        const float* __restrict__ aggv, const float* __restrict__ wv,
        const float* __restrict__ wvo, const float* __restrict__ vec,
        const float* __restrict__ pos, float* __restrict__ out) {
    int node0 = blockIdx.x * 4;
    int tid = threadIdx.x;
    int k = tid >> 6, t = tid & 63;
    int node = node0 + k;
    __shared__ float avh[4][48];
    __shared__ float vn[4][48];
    if (t < 48) {
        float a = 0.f;
#pragma unroll
        for (int p = 0; p < 8; ++p) a += aggv[(size_t)p * 98304 + node * 48 + t];
        avh[k][t] = a;
    }
    __syncthreads();
    if (t < 48) {
        int e = t / 3, d = t % 3;
        float acc = 0.f;
#pragma unroll
        for (int c = 0; c < 16; ++c) acc += avh[k][c * 3 + d] * wv[c * 16 + e];
        vn[k][t] = (vec[node * 48 + t] + acc) * wvo[e];
    }
    __syncthreads();
    if (t < 3) {
        float acc = 0.f;
#pragma unroll
        for (int e = 0; e < 16; ++e) acc += vn[k][e * 3 + t];
        out[node * 3 + t] = acc + pos[node * 3 + t];
    }
}

extern "C" void kernel_launch(void* const* d_in, const int* in_sizes, int n_in,
                              void* d_out, int out_size, void* d_ws, size_t ws_size,
                              hipStream_t stream) {
    const float* pos = (const float*)d_in[0];
    const float* v   = (const float*)d_in[1];
    const float* z   = (const float*)d_in[2];
    const float* w_s_in = (const float*)d_in[3];
    const float* w_v_in = (const float*)d_in[4];
    const float* rw1 = (const float*)d_in[5];
    const float* rb1 = (const float*)d_in[6];
    const float* rw2 = (const float*)d_in[7];
    const float* rb2 = (const float*)d_in[8];
    const float* sws = (const float*)d_in[9];
    const float* swv = (const float*)d_in[10];
    const float* wvo = (const float*)d_in[11];
    float* out = (float*)d_out;

    float* wsf = (float*)d_ws;
    float* sA = wsf + SA_OFF;
    float* vA = wsf + VA_OFF;
    float* sB = wsf + SB_OFF;
    float* vB = wsf + VB_OFF;
    float* aggsA = wsf + AGGSA_OFF;
    float* aggvA = wsf + AGGVA_OFF;
    float* aggsB = wsf + AGGSB_OFF;
    float* aggvB = wsf + AGGVB_OFF;

    // L0: init state -> sA/vA, edge -> aggsA/aggvA
    k_medge<0><<<512, 256, 0, stream>>>(pos, z, v, w_s_in, w_v_in,
                                        sws, swv, sA, vA, sA, vA,
                                        aggsB, aggvB,
                                        rw2, rb2, rw1, rb1,
                                        aggsA, aggvA);
    // L1: update(aggsA)+residual(sA) -> sB/vB, edge -> aggsB/aggvB
    k_medge<1><<<512, 256, 0, stream>>>(pos, z, v, w_s_in, w_v_in,
                                        sws, swv, sA, vA, sB, vB,
                                        aggsA, aggvA,
                                        rw2 + 32768, rb2 + 1024, rw1 + 32, rb1 + 32,
                                        aggsB, aggvB);
    // L2: update(aggsB)+residual(sB) (no state write), edge -> aggsA/aggvA
    k_medge<2><<<512, 256, 0, stream>>>(pos, z, v, w_s_in, w_v_in,
                                        sws + 256, swv + 256, sB, vB, sA, vA,
                                        aggsB, aggvB,
                                        rw2 + 65536, rb2 + 2048, rw1 + 64, rb1 + 64,
                                        aggsA, aggvA);
    // out: vec_L1 (vB) + L2 partials (aggvA)
    k_out<<<512, 256, 0, stream>>>(aggvA, swv + 512, wvo, vB, pos, out);
}

// Round 17
// 67.438 us; speedup vs baseline: 1.7514x; 1.1325x over previous
//
#include <hip/hip_runtime.h>

#define NF 16
#define NB 32
#define NN 64
#define EPSV 1e-8f

typedef _Float16 f16x8 __attribute__((ext_vector_type(8)));
typedef _Float16 f16x2 __attribute__((ext_vector_type(2)));
typedef __fp16 fp16x2 __attribute__((ext_vector_type(2)));
typedef float f32x4 __attribute__((ext_vector_type(4)));

// Workspace (float offsets), ping-pong buffers, all overwritten before read:
#define SA_OFF    0
#define VA_OFF    32768
#define SB_OFF    131072
#define VB_OFF    163840
#define AGGSA_OFF 262144
#define AGGVA_OFF 524288
#define AGGSB_OFF 1310720
#define AGGVB_OFF 1572864

__device__ __forceinline__ f16x2 cvt_pk(float a, float b) {
    fp16x2 r = __builtin_amdgcn_cvt_pkrtz(a, b);
    return __builtin_bit_cast(f16x2, r);
}

__device__ __forceinline__ f16x8 pack8(f16x2 a, f16x2 b, f16x2 c, f16x2 d) {
    f16x8 r;
    r[0] = a[0]; r[1] = a[1]; r[2] = b[0]; r[3] = b[1];
    r[4] = c[0]; r[5] = c[1]; r[6] = d[0]; r[7] = d[1];
    return r;
}

// Merged per-layer kernel: [update from prev partials] + A2/B2 build (LDS) + edge.
// grid 512 = 8 xcd * 4 b * 8 sgrp * 2 fhalf; block owns 8 src nodes, all 64 dst.
// W2 half-tile preloaded ONCE into registers at kernel top. Lane map fh=tid&63,
// hq8=tid>>6: each wave has a FIXED hq8, so W2 load instructions touch 4
// contiguous 512B segments instead of ~32 isolated lines (coalescer-friendly).
template <int LAYER>
__global__ __launch_bounds__(256, 2) void k_medge(
        const float* __restrict__ pos,
        const float* __restrict__ z, const float* __restrict__ v,
        const float* __restrict__ w_s_in, const float* __restrict__ w_v_in,
        const float* __restrict__ sws_l, const float* __restrict__ swv_l,
        const float* __restrict__ sprev, const float* __restrict__ vprev,
        float* __restrict__ snew, float* __restrict__ vnew,
        const float* __restrict__ aggs_in, const float* __restrict__ aggv_in,
        const float* __restrict__ W2, const float* __restrict__ b2,
        const float* __restrict__ w1, const float* __restrict__ b1,
        float* __restrict__ aggs_out, float* __restrict__ aggv_out) {
    int blk = blockIdx.x;
    int xcd = blk & 7;
    int t = blk >> 3;                    // 0..63
    int b = xcd * 4 + (t >> 4);
    int rem = t & 15;
    int sgrp = rem >> 1, wfh = rem & 1;
    int tid = threadIdx.x;
    int nbase = b * NN + sgrp * 8;       // this block's 8 src nodes

    __shared__ float pos_sh[NN * 3];
    __shared__ float s_sh[8][16];
    __shared__ float vec_t[3][8][16];    // [d][node][channel]
    __shared__ float aggfull[8][64];
    __shared__ float sigA_sh[8];
    __shared__ int eexp_sh[8];
    __shared__ _Float16 A2sh[8][2048];   // [src][chunk*8], chunk swizzled
    __shared__ float B2sh[8][64];

    if (tid < NN * 3) pos_sh[tid] = pos[(size_t)b * NN * 3 + tid];

    // ---- W2/b2 preload (once, hoisted): wave-uniform hq8 => coalesced segs ----
    int fh_p = tid & 63, hq8_p = tid >> 6;   // fh 0..63 within half, h-octet/wave
    int fg_p = wfh * 64 + fh_p;
    int i_p = fg_p >> 3, cc_p = fg_p & 7;
    int strm_p = (cc_p == 0) ? 0 : (cc_p == 1) ? 1 : (cc_p <= 4) ? 2 : 3;
    int dd_p = (cc_p <= 1) ? 0 : (cc_p <= 4 ? cc_p - 2 : cc_p - 5);
    const float* wp_p = W2 + (size_t)(hq8_p * 8) * 1024 + strm_p * 256 + i_p * 16;
    float4 wr_all[8][4];
#pragma unroll
    for (int h8 = 0; h8 < 8; ++h8) {
        const float4* w4 = (const float4*)(wp_p + h8 * 1024);
        wr_all[h8][0] = w4[0]; wr_all[h8][1] = w4[1];
        wr_all[h8][2] = w4[2]; wr_all[h8][3] = w4[3];
    }
    float4 bw_p[4];
    if (hq8_p == 0) {
        const float4* bp = (const float4*)(b2 + strm_p * 256 + i_p * 16);
        bw_p[0] = bp[0]; bw_p[1] = bp[1]; bw_p[2] = bp[2]; bw_p[3] = bp[3];
    }

    // ---- state phase: init (L0) or update from prev partials (L1,L2) ----
    if (LAYER == 0) {
        for (int it = tid; it < 512; it += 256) {
            int k = it >> 6, ch = it & 63;
            int node = nbase + k;
            if (ch < 16) {
                float val = z[node] * w_s_in[ch];
                s_sh[k][ch] = val;
                if (wfh == 0) snew[node * 16 + ch] = val;
            } else {
                int q = ch - 16, e = q / 3, d = q % 3;
                float val = v[node * 3 + d] * w_v_in[e];
                vec_t[d][k][e] = val;
                if (wfh == 0) vnew[node * 48 + q] = val;
            }
        }
    } else {
        for (int it = tid; it < 512; it += 256) {
            int k = it >> 6, ch = it & 63;
            int node = nbase + k;
            float a = 0.f;
            if (ch < 16) {
#pragma unroll
                for (int p = 0; p < 8; ++p) a += aggs_in[(size_t)p * 32768 + node * 16 + ch];
            } else {
#pragma unroll
                for (int p = 0; p < 8; ++p) a += aggv_in[(size_t)p * 98304 + node * 48 + (ch - 16)];
            }
            aggfull[k][ch] = a;
        }
        __syncthreads();
        for (int it = tid; it < 512; it += 256) {
            int k = it >> 6, ch = it & 63;
            int node = nbase + k;
            if (ch < 16) {
                float acc = 0.f;
#pragma unroll
                for (int c = 0; c < 16; ++c) acc += aggfull[k][c] * sws_l[c * 16 + ch];
                float val = sprev[node * 16 + ch] + fmaxf(acc, 0.f);
                s_sh[k][ch] = val;
                if (LAYER == 1 && wfh == 0) snew[node * 16 + ch] = val;
            } else {
                int q = ch - 16, e = q / 3, d = q % 3;
                float acc = 0.f;
#pragma unroll
                for (int c = 0; c < 16; ++c) acc += aggfull[k][16 + c * 3 + d] * swv_l[c * 16 + e];
                float val = vprev[node * 48 + q] + acc;
                vec_t[d][k][e] = val;
                if (LAYER == 1 && wfh == 0) vnew[node * 48 + q] = val;
            }
        }
    }
    __syncthreads();

    // ---- per-node scale exponent (block-local) ----
    if (tid < 8) {
        float m = 0.f;
#pragma unroll
        for (int j = 0; j < 16; ++j) m = fmaxf(m, fabsf(s_sh[tid][j]));
#pragma unroll
        for (int d = 0; d < 3; ++d)
#pragma unroll
            for (int e = 0; e < 16; ++e) m = fmaxf(m, fabsf(vec_t[d][tid][e]));
        unsigned mb = __float_as_uint(m);
        int ex = (int)((mb >> 23) & 0xFF);
        eexp_sh[tid] = ex - 126;
        sigA_sh[tid] = __uint_as_float((unsigned)(253 - ex) << 23);  // 2^(126-ex)
    }
    __syncthreads();

    // ---- pre phase: single k2 sweep; W2 already in registers; same stores ----
    {
        int mt = fh_p >> 4, colw = fh_p & 15;
        int chunk = mt * 64 + hq8_p * 16 + ((colw + hq8_p * 4) & 15);  // bank swizzle
#pragma unroll
        for (int k2 = 0; k2 < 8; ++k2) {
            const float* srcp = (strm_p <= 1) ? &s_sh[k2][0] : &vec_t[dd_p][k2][0];
            const float4* f4 = (const float4*)srcp;
            float4 f0 = f4[0], f1 = f4[1], f2 = f4[2], f3 = f4[3];
            float sA = sigA_sh[k2];
            f16x8 st;
#pragma unroll
            for (int h8 = 0; h8 < 8; ++h8) {
                float4 a0 = wr_all[h8][0], a1 = wr_all[h8][1];
                float4 a2 = wr_all[h8][2], a3 = wr_all[h8][3];
                float acc = a0.x * f0.x + a0.y * f0.y + a0.z * f0.z + a0.w * f0.w
                          + a1.x * f1.x + a1.y * f1.y + a1.z * f1.z + a1.w * f1.w
                          + a2.x * f2.x + a2.y * f2.y + a2.z * f2.z + a2.w * f2.w
                          + a3.x * f3.x + a3.y * f3.y + a3.z * f3.z + a3.w * f3.w;
                st[h8] = (_Float16)(acc * sA);
            }
            *(f16x8*)&A2sh[k2][chunk * 8] = st;
            if (hq8_p == 0) {
                float accb = bw_p[0].x * f0.x + bw_p[0].y * f0.y + bw_p[0].z * f0.z + bw_p[0].w * f0.w
                           + bw_p[1].x * f1.x + bw_p[1].y * f1.y + bw_p[1].z * f1.z + bw_p[1].w * f1.w
                           + bw_p[2].x * f2.x + bw_p[2].y * f2.y + bw_p[2].z * f2.z + bw_p[2].w * f2.w
                           + bw_p[3].x * f3.x + bw_p[3].y * f3.y + bw_p[3].z * f3.z + bw_p[3].w * f3.w;
                B2sh[k2][fh_p] = accb;   // unscaled
            }
        }
    }
    __syncthreads();

    // ---- edge phase: 4 waves x 16 dst cols, MFMA over 8 srcs from LDS ----
    {
        int wd = tid >> 6;
        int lane = tid & 63;
        int q = lane >> 4, col = lane & 15;
        int dst = wd * 16 + col;
        float qodd = (float)(q & 1);
        float o1 = qodd;

        float pdx = pos_sh[dst * 3 + 0], pdy = pos_sh[dst * 3 + 1], pdz = pos_sh[dst * 3 + 2];
        float w1r[8], b1r[8];
#pragma unroll
        for (int j = 0; j < 8; ++j) { w1r[j] = w1[q * 8 + j]; b1r[j] = b1[q * 8 + j]; }

        int es[8], eblk = -10000;
#pragma unroll
        for (int j = 0; j < 8; ++j) {
            es[j] = eexp_sh[j];
            eblk = es[j] > eblk ? es[j] : eblk;
        }
        float invsb = __uint_as_float((unsigned)(127 + eblk) << 23);  // 2^eblk

        f32x4 acc[4][4];
#pragma unroll
        for (int mt = 0; mt < 4; ++mt)
#pragma unroll
            for (int u = 0; u < 4; ++u) acc[mt][u] = (f32x4){0.f, 0.f, 0.f, 0.f};
        float ms_p[4] = {0.f, 0.f, 0.f, 0.f};
        float mv_p[4][3];
#pragma unroll
        for (int mt = 0; mt < 4; ++mt) { mv_p[mt][0] = 0.f; mv_p[mt][1] = 0.f; mv_p[mt][2] = 0.f; }

        for (int j = 0; j < 8; ++j) {
            int src = sgrp * 8 + j;
            float psx = pos_sh[src * 3 + 0];
            float psy = pos_sh[src * 3 + 1];
            float psz = pos_sh[src * 3 + 2];
            float dx = pdx - psx, dy = pdy - psy, dz = pdz - psz;
            float r = __builtin_amdgcn_sqrtf(dx * dx + dy * dy + dz * dz);
            float inv = __builtin_amdgcn_rcpf(r + EPSV);
            float ux = dx * inv, uy = dy * inv, uz = dz * inv;
            float vmask = (dst == src) ? 0.f : 1.f;

            int dEx = es[j] - eblk;
            float sc2 = (dEx < -120) ? 0.f : __uint_as_float((unsigned)(127 + dEx) << 23);
            float scl = sc2 * vmask;

            f16x2 ux2 = {(_Float16)ux, (_Float16)ux};
            f16x2 uy2 = {(_Float16)uy, (_Float16)uy};
            f16x2 uz2 = {(_Float16)uz, (_Float16)uz};
            f16x2 p0[4], p1[4], p2[4], p3[4];
#pragma unroll
            for (int jp = 0; jp < 4; ++jp) {
                float h0 = fmaxf(fmaf(r, w1r[2 * jp],     b1r[2 * jp]),     0.f) * scl;
                float h1 = fmaxf(fmaf(r, w1r[2 * jp + 1], b1r[2 * jp + 1]), 0.f) * scl;
                p0[jp] = cvt_pk(h0, h1);
                p1[jp] = p0[jp] * ux2;
                p2[jp] = p0[jp] * uy2;
                p3[jp] = p0[jp] * uz2;
            }
            f16x8 bf0 = pack8(p0[0], p0[1], p0[2], p0[3]);
            f16x8 bf1 = pack8(p1[0], p1[1], p1[2], p1[3]);
            f16x8 bf2 = pack8(p2[0], p2[1], p2[2], p2[3]);
            f16x8 bf3 = pack8(p3[0], p3[1], p3[2], p3[3]);

#pragma unroll
            for (int mt = 0; mt < 4; ++mt) {
                f16x8 af = *(const f16x8*)&A2sh[j][(mt * 64 + q * 16 + ((col + q * 4) & 15)) * 8];
                acc[mt][0] = __builtin_amdgcn_mfma_f32_16x16x32_f16(af, bf0, acc[mt][0], 0, 0, 0);
                acc[mt][1] = __builtin_amdgcn_mfma_f32_16x16x32_f16(af, bf1, acc[mt][1], 0, 0, 0);
                acc[mt][2] = __builtin_amdgcn_mfma_f32_16x16x32_f16(af, bf2, acc[mt][2], 0, 0, 0);
                acc[mt][3] = __builtin_amdgcn_mfma_f32_16x16x32_f16(af, bf3, acc[mt][3], 0, 0, 0);
            }

            float s0  = qodd ? uz : 1.f;
            float zx  = qodd ? 0.f : ux;
            float zy  = qodd ? 0.f : uy;
            float exu = qodd ? 1.f : ux;
            float euy = qodd ? 0.f : uy;
            float euz = qodd ? 0.f : uz;
#pragma unroll
            for (int mt = 0; mt < 4; ++mt) {
                float4 bv = *(const float4*)&B2sh[j][mt * 16 + q * 4];
                float t0 = bv.x * vmask, t1 = bv.y * vmask, t2 = bv.z * vmask, t3 = bv.w * vmask;
                ms_p[mt]    += t0 * s0 + t2 * zx + t3 * zy;
                mv_p[mt][0] += t1 * exu;
                mv_p[mt][1] += t1 * euy + t2 * o1;
                mv_p[mt][2] += t1 * euz + t3 * o1;
            }
        }

#pragma unroll
        for (int mt = 0; mt < 4; ++mt) {
            float fs, fv0, fv1, fv2;
            if ((q & 1) == 0) {
                fs  = acc[mt][0][0] + acc[mt][1][2] + acc[mt][2][3];
                fv0 = acc[mt][1][1]; fv1 = acc[mt][2][1]; fv2 = acc[mt][3][1];
            } else {
                fs  = acc[mt][3][0];
                fv0 = acc[mt][0][1]; fv1 = acc[mt][0][2]; fv2 = acc[mt][0][3];
            }
            ms_p[mt]    += fs  * invsb;
            mv_p[mt][0] += fv0 * invsb;
            mv_p[mt][1] += fv1 * invsb;
            mv_p[mt][2] += fv2 * invsb;
        }

        // single xor-16 reduce (q pairs hold complementary cc-streams of same channel)
#pragma unroll
        for (int mt = 0; mt < 4; ++mt) {
            ms_p[mt]    += __shfl_xor(ms_p[mt], 16, 64);
            mv_p[mt][0] += __shfl_xor(mv_p[mt][0], 16, 64);
            mv_p[mt][1] += __shfl_xor(mv_p[mt][1], 16, 64);
            mv_p[mt][2] += __shfl_xor(mv_p[mt][2], 16, 64);
        }

        if ((q & 1) == 0) {
            int nodeD = b * NN + dst;
#pragma unroll
            for (int mt = 0; mt < 4; ++mt) {
                int i2 = (wfh * 4 + mt) * 2 + (q >> 1);
                aggs_out[(size_t)sgrp * 32768 + nodeD * 16 + i2] = ms_p[mt];
                float* vp = aggv_out + (size_t)sgrp * 98304 + nodeD * 48 + i2 * 3;
                vp[0] = mv_p[mt][0]; vp[1] = mv_p[mt][1]; vp[2] = mv_p[mt][2];
            }
        }
    }
}

__global__ __launch_bounds__(256) void k_out(
        const float* __restrict__ aggv, const float* __restrict__ wv,
        const float* __restrict__ wvo, const float* __restrict__ vec,
        const float* __restrict__ pos, float* __restrict__ out) {
    int node0 = blockIdx.x * 4;
    int tid = threadIdx.x;
    int k = tid >> 6, t = tid & 63;
    int node = node0 + k;
    __shared__ float avh[4][48];
    __shared__ float vn[4][48];
    if (t < 48) {
        float a = 0.f;
#pragma unroll
        for (int p = 0; p < 8; ++p) a += aggv[(size_t)p * 98304 + node * 48 + t];
        avh[k][t] = a;
    }
    __syncthreads();
    if (t < 48) {
        int e = t / 3, d = t % 3;
        float acc = 0.f;
#pragma unroll
        for (int c = 0; c < 16; ++c) acc += avh[k][c * 3 + d] * wv[c * 16 + e];
        vn[k][t] = (vec[node * 48 + t] + acc) * wvo[e];
    }
    __syncthreads();
    if (t < 3) {
        float acc = 0.f;
#pragma unroll
        for (int e = 0; e < 16; ++e) acc += vn[k][e * 3 + t];
        out[node * 3 + t] = acc + pos[node * 3 + t];
    }
}

extern "C" void kernel_launch(void* const* d_in, const int* in_sizes, int n_in,
                              void* d_out, int out_size, void* d_ws, size_t ws_size,
                              hipStream_t stream) {
    const float* pos = (const float*)d_in[0];
    const float* v   = (const float*)d_in[1];
    const float* z   = (const float*)d_in[2];
    const float* w_s_in = (const float*)d_in[3];
    const float* w_v_in = (const float*)d_in[4];
    const float* rw1 = (const float*)d_in[5];
    const float* rb1 = (const float*)d_in[6];
    const float* rw2 = (const float*)d_in[7];
    const float* rb2 = (const float*)d_in[8];
    const float* sws = (const float*)d_in[9];
    const float* swv = (const float*)d_in[10];
    const float* wvo = (const float*)d_in[11];
    float* out = (float*)d_out;

    float* wsf = (float*)d_ws;
    float* sA = wsf + SA_OFF;
    float* vA = wsf + VA_OFF;
    float* sB = wsf + SB_OFF;
    float* vB = wsf + VB_OFF;
    float* aggsA = wsf + AGGSA_OFF;
    float* aggvA = wsf + AGGVA_OFF;
    float* aggsB = wsf + AGGSB_OFF;
    float* aggvB = wsf + AGGVB_OFF;

    // L0: init state -> sA/vA, edge -> aggsA/aggvA
    k_medge<0><<<512, 256, 0, stream>>>(pos, z, v, w_s_in, w_v_in,
                                        sws, swv, sA, vA, sA, vA,
                                        aggsB, aggvB,
                                        rw2, rb2, rw1, rb1,
                                        aggsA, aggvA);
    // L1: update(aggsA)+residual(sA) -> sB/vB, edge -> aggsB/aggvB
    k_medge<1><<<512, 256, 0, stream>>>(pos, z, v, w_s_in, w_v_in,
                                        sws, swv, sA, vA, sB, vB,
                                        aggsA, aggvA,
                                        rw2 + 32768, rb2 + 1024, rw1 + 32, rb1 + 32,
                                        aggsB, aggvB);
    // L2: update(aggsB)+residual(sB) (no state write), edge -> aggsA/aggvA
    k_medge<2><<<512, 256, 0, stream>>>(pos, z, v, w_s_in, w_v_in,
                                        sws + 256, swv + 256, sB, vB, sA, vA,
                                        aggsB, aggvB,
                                        rw2 + 65536, rb2 + 2048, rw1 + 64, rb1 + 64,
                                        aggsA, aggvA);
    // out: vec_L1 (vB) + L2 partials (aggvA)
    k_out<<<512, 256, 0, stream>>>(aggvA, swv + 512, wvo, vB, pos, out);
}

// Round 19
// 66.397 us; speedup vs baseline: 1.7789x; 1.0157x over previous
//
#include <hip/hip_runtime.h>

#define NF 16
#define NB 32
#define NN 64
#define EPSV 1e-8f

typedef _Float16 f16x8 __attribute__((ext_vector_type(8)));
typedef _Float16 f16x2 __attribute__((ext_vector_type(2)));
typedef __fp16 fp16x2 __attribute__((ext_vector_type(2)));
typedef float f32x4 __attribute__((ext_vector_type(4)));

// Workspace (float offsets), ping-pong buffers, all overwritten before read:
#define SA_OFF    0
#define VA_OFF    32768
#define SB_OFF    131072
#define VB_OFF    163840
#define AGGSA_OFF 262144
#define AGGVA_OFF 524288
#define AGGSB_OFF 1310720
#define AGGVB_OFF 1572864
#define W2R_OFF   2359296   // 3*65536 floats: dense-load relayout (rows duplicated per cc)

__device__ __forceinline__ f16x2 cvt_pk(float a, float b) {
    fp16x2 r = __builtin_amdgcn_cvt_pkrtz(a, b);
    return __builtin_bit_cast(f16x2, r);
}

__device__ __forceinline__ f16x8 pack8(f16x2 a, f16x2 b, f16x2 c, f16x2 d) {
    f16x8 r;
    r[0] = a[0]; r[1] = a[1]; r[2] = b[0]; r[3] = b[1];
    r[4] = c[0]; r[5] = c[1]; r[6] = d[0]; r[7] = d[1];
    return r;
}

__device__ __forceinline__ int strm_of(int cc) {
    return (cc == 0) ? 0 : (cc == 1) ? 1 : (cc <= 4) ? 2 : 3;
}

// Relayout rw2 (3 layers) into dense-load order (16384 float4 per layer):
// float4 index = ((((l*2+wfh)*4+hq8)*8+h8)*4+jq)*64 + fh
//   <- rw2[l*32768 + (hq8*8+h8)*1024 + strm(fg)*256 + (fg>>3)*16 + jq*4 ...],
//   fg = wfh*64 + fh.  One float4 per thread; writes fully coalesced.
__global__ __launch_bounds__(256) void k_w2r(const float* __restrict__ rw2,
                                             float* __restrict__ W2R) {
    int idx = blockIdx.x * 256 + threadIdx.x;   // 0..49151 (192 blocks)
    int fh  = idx & 63;
    int jq  = (idx >> 6) & 3;
    int h8  = (idx >> 8) & 7;
    int hq8 = (idx >> 11) & 3;
    int wfh = (idx >> 13) & 1;
    int l   = idx >> 14;                        // 16384 float4s per layer
    int fg = wfh * 64 + fh;
    int i = fg >> 3, cc = fg & 7;
    int h = hq8 * 8 + h8;
    const float4* src = (const float4*)(rw2 + (size_t)l * 32768 + h * 1024
                                        + strm_of(cc) * 256 + i * 16 + jq * 4);
    ((float4*)W2R)[idx] = *src;
}

// Merged per-layer kernel: [update from prev partials] + A2/B2 build (LDS) + edge.
// grid 512 = 8 xcd * 4 b * 8 sgrp * 2 fhalf; block owns 8 src nodes, all 64 dst.
// W2 half-tile preloaded ONCE from the dense relayout: every load instruction
// reads 64 lanes x 16B fully contiguous (single coalesced burst).
template <int LAYER>
__global__ __launch_bounds__(256, 2) void k_medge(
        const float* __restrict__ pos,
        const float* __restrict__ z, const float* __restrict__ v,
        const float* __restrict__ w_s_in, const float* __restrict__ w_v_in,
        const float* __restrict__ sws_l, const float* __restrict__ swv_l,
        const float* __restrict__ sprev, const float* __restrict__ vprev,
        float* __restrict__ snew, float* __restrict__ vnew,
        const float* __restrict__ aggs_in, const float* __restrict__ aggv_in,
        const float* __restrict__ W2R, const float* __restrict__ b2,
        const float* __restrict__ w1, const float* __restrict__ b1,
        float* __restrict__ aggs_out, float* __restrict__ aggv_out) {
    int blk = blockIdx.x;
    int xcd = blk & 7;
    int t = blk >> 3;                    // 0..63
    int b = xcd * 4 + (t >> 4);
    int rem = t & 15;
    int sgrp = rem >> 1, wfh = rem & 1;
    int tid = threadIdx.x;
    int nbase = b * NN + sgrp * 8;       // this block's 8 src nodes

    __shared__ float pos_sh[NN * 3];
    __shared__ float s_sh[8][16];
    __shared__ float vec_t[3][8][16];    // [d][node][channel]
    __shared__ float aggfull[8][64];
    __shared__ float sigA_sh[8];
    __shared__ int eexp_sh[8];
    __shared__ _Float16 A2sh[8][2048];   // [src][chunk*8], chunk swizzled
    __shared__ float B2sh[8][64];

    if (tid < NN * 3) pos_sh[tid] = pos[(size_t)b * NN * 3 + tid];

    // ---- W2/b2 preload (once, hoisted): dense relayout => perfect coalescing ----
    int fh_p = tid & 63, hq8_p = tid >> 6;   // fh 0..63 within half, h-octet/wave
    int fg_p = wfh * 64 + fh_p;
    int i_p = fg_p >> 3, cc_p = fg_p & 7;
    int strm_p = strm_of(cc_p);
    int dd_p = (cc_p <= 1) ? 0 : (cc_p <= 4 ? cc_p - 2 : cc_p - 5);
    const float* wp_p = W2R + (size_t)(((LAYER * 2 + wfh) * 4 + hq8_p) * 8) * 1024
                        + fh_p * 4;
    float4 wr_all[8][4];
#pragma unroll
    for (int h8 = 0; h8 < 8; ++h8) {
#pragma unroll
        for (int jq = 0; jq < 4; ++jq) {
            wr_all[h8][jq] = *(const float4*)(wp_p + (h8 * 4 + jq) * 256);
        }
    }
    float4 bw_p[4];
    if (hq8_p == 0) {
        const float4* bp = (const float4*)(b2 + strm_p * 256 + i_p * 16);
        bw_p[0] = bp[0]; bw_p[1] = bp[1]; bw_p[2] = bp[2]; bw_p[3] = bp[3];
    }

    // ---- state phase: init (L0) or update from prev partials (L1,L2) ----
    if (LAYER == 0) {
        for (int it = tid; it < 512; it += 256) {
            int k = it >> 6, ch = it & 63;
            int node = nbase + k;
            if (ch < 16) {
                float val = z[node] * w_s_in[ch];
                s_sh[k][ch] = val;
                if (wfh == 0) snew[node * 16 + ch] = val;
            } else {
                int q = ch - 16, e = q / 3, d = q % 3;
                float val = v[node * 3 + d] * w_v_in[e];
                vec_t[d][k][e] = val;
                if (wfh == 0) vnew[node * 48 + q] = val;
            }
        }
    } else {
        for (int it = tid; it < 512; it += 256) {
            int k = it >> 6, ch = it & 63;
            int node = nbase + k;
            float a = 0.f;
            if (ch < 16) {
#pragma unroll
                for (int p = 0; p < 8; ++p) a += aggs_in[(size_t)p * 32768 + node * 16 + ch];
            } else {
#pragma unroll
                for (int p = 0; p < 8; ++p) a += aggv_in[(size_t)p * 98304 + node * 48 + (ch - 16)];
            }
            aggfull[k][ch] = a;
        }
        __syncthreads();
        for (int it = tid; it < 512; it += 256) {
            int k = it >> 6, ch = it & 63;
            int node = nbase + k;
            if (ch < 16) {
                float acc = 0.f;
#pragma unroll
                for (int c = 0; c < 16; ++c) acc += aggfull[k][c] * sws_l[c * 16 + ch];
                float val = sprev[node * 16 + ch] + fmaxf(acc, 0.f);
                s_sh[k][ch] = val;
                if (LAYER == 1 && wfh == 0) snew[node * 16 + ch] = val;
            } else {
                int q = ch - 16, e = q / 3, d = q % 3;
                float acc = 0.f;
#pragma unroll
                for (int c = 0; c < 16; ++c) acc += aggfull[k][16 + c * 3 + d] * swv_l[c * 16 + e];
                float val = vprev[node * 48 + q] + acc;
                vec_t[d][k][e] = val;
                if (LAYER == 1 && wfh == 0) vnew[node * 48 + q] = val;
            }
        }
    }
    __syncthreads();

    // ---- per-node scale exponent (block-local) ----
    if (tid < 8) {
        float m = 0.f;
#pragma unroll
        for (int j = 0; j < 16; ++j) m = fmaxf(m, fabsf(s_sh[tid][j]));
#pragma unroll
        for (int d = 0; d < 3; ++d)
#pragma unroll
            for (int e = 0; e < 16; ++e) m = fmaxf(m, fabsf(vec_t[d][tid][e]));
        unsigned mb = __float_as_uint(m);
        int ex = (int)((mb >> 23) & 0xFF);
        eexp_sh[tid] = ex - 126;
        sigA_sh[tid] = __uint_as_float((unsigned)(253 - ex) << 23);  // 2^(126-ex)
    }
    __syncthreads();

    // ---- pre phase: single k2 sweep; W2 already in registers; same stores ----
    {
        int mt = fh_p >> 4, colw = fh_p & 15;
        int chunk = mt * 64 + hq8_p * 16 + ((colw + hq8_p * 4) & 15);  // bank swizzle
#pragma unroll
        for (int k2 = 0; k2 < 8; ++k2) {
            const float* srcp = (strm_p <= 1) ? &s_sh[k2][0] : &vec_t[dd_p][k2][0];
            const float4* f4 = (const float4*)srcp;
            float4 f0 = f4[0], f1 = f4[1], f2 = f4[2], f3 = f4[3];
            float sA = sigA_sh[k2];
            f16x8 st;
#pragma unroll
            for (int h8 = 0; h8 < 8; ++h8) {
                float4 a0 = wr_all[h8][0], a1 = wr_all[h8][1];
                float4 a2 = wr_all[h8][2], a3 = wr_all[h8][3];
                float acc = a0.x * f0.x + a0.y * f0.y + a0.z * f0.z + a0.w * f0.w
                          + a1.x * f1.x + a1.y * f1.y + a1.z * f1.z + a1.w * f1.w
                          + a2.x * f2.x + a2.y * f2.y + a2.z * f2.z + a2.w * f2.w
                          + a3.x * f3.x + a3.y * f3.y + a3.z * f3.z + a3.w * f3.w;
                st[h8] = (_Float16)(acc * sA);
            }
            *(f16x8*)&A2sh[k2][chunk * 8] = st;
            if (hq8_p == 0) {
                float accb = bw_p[0].x * f0.x + bw_p[0].y * f0.y + bw_p[0].z * f0.z + bw_p[0].w * f0.w
                           + bw_p[1].x * f1.x + bw_p[1].y * f1.y + bw_p[1].z * f1.z + bw_p[1].w * f1.w
                           + bw_p[2].x * f2.x + bw_p[2].y * f2.y + bw_p[2].z * f2.z + bw_p[2].w * f2.w
                           + bw_p[3].x * f3.x + bw_p[3].y * f3.y + bw_p[3].z * f3.z + bw_p[3].w * f3.w;
                B2sh[k2][fh_p] = accb;   // unscaled
            }
        }
    }
    __syncthreads();

    // ---- edge phase: 4 waves x 16 dst cols, MFMA over 8 srcs from LDS ----
    {
        int wd = tid >> 6;
        int lane = tid & 63;
        int q = lane >> 4, col = lane & 15;
        int dst = wd * 16 + col;
        float qodd = (float)(q & 1);
        float o1 = qodd;

        float pdx = pos_sh[dst * 3 + 0], pdy = pos_sh[dst * 3 + 1], pdz = pos_sh[dst * 3 + 2];
        float w1r[8], b1r[8];
#pragma unroll
        for (int j = 0; j < 8; ++j) { w1r[j] = w1[q * 8 + j]; b1r[j] = b1[q * 8 + j]; }

        int es[8], eblk = -10000;
#pragma unroll
        for (int j = 0; j < 8; ++j) {
            es[j] = eexp_sh[j];
            eblk = es[j] > eblk ? es[j] : eblk;
        }
        float invsb = __uint_as_float((unsigned)(127 + eblk) << 23);  // 2^eblk

        f32x4 acc[4][4];
#pragma unroll
        for (int mt = 0; mt < 4; ++mt)
#pragma unroll
            for (int u = 0; u < 4; ++u) acc[mt][u] = (f32x4){0.f, 0.f, 0.f, 0.f};
        float ms_p[4] = {0.f, 0.f, 0.f, 0.f};
        float mv_p[4][3];
#pragma unroll
        for (int mt = 0; mt < 4; ++mt) { mv_p[mt][0] = 0.f; mv_p[mt][1] = 0.f; mv_p[mt][2] = 0.f; }

        for (int j = 0; j < 8; ++j) {
            int src = sgrp * 8 + j;
            float psx = pos_sh[src * 3 + 0];
            float psy = pos_sh[src * 3 + 1];
            float psz = pos_sh[src * 3 + 2];
            float dx = pdx - psx, dy = pdy - psy, dz = pdz - psz;
            float r = __builtin_amdgcn_sqrtf(dx * dx + dy * dy + dz * dz);
            float inv = __builtin_amdgcn_rcpf(r + EPSV);
            float ux = dx * inv, uy = dy * inv, uz = dz * inv;
            float vmask = (dst == src) ? 0.f : 1.f;

            int dEx = es[j] - eblk;
            float sc2 = (dEx < -120) ? 0.f : __uint_as_float((unsigned)(127 + dEx) << 23);
            float scl = sc2 * vmask;

            f16x2 ux2 = {(_Float16)ux, (_Float16)ux};
            f16x2 uy2 = {(_Float16)uy, (_Float16)uy};
            f16x2 uz2 = {(_Float16)uz, (_Float16)uz};
            f16x2 p0[4], p1[4], p2[4], p3[4];
#pragma unroll
            for (int jp = 0; jp < 4; ++jp) {
                float h0 = fmaxf(fmaf(r, w1r[2 * jp],     b1r[2 * jp]),     0.f) * scl;
                float h1 = fmaxf(fmaf(r, w1r[2 * jp + 1], b1r[2 * jp + 1]), 0.f) * scl;
                p0[jp] = cvt_pk(h0, h1);
                p1[jp] = p0[jp] * ux2;
                p2[jp] = p0[jp] * uy2;
                p3[jp] = p0[jp] * uz2;
            }
            f16x8 bf0 = pack8(p0[0], p0[1], p0[2], p0[3]);
            f16x8 bf1 = pack8(p1[0], p1[1], p1[2], p1[3]);
            f16x8 bf2 = pack8(p2[0], p2[1], p2[2], p2[3]);
            f16x8 bf3 = pack8(p3[0], p3[1], p3[2], p3[3]);

#pragma unroll
            for (int mt = 0; mt < 4; ++mt) {
                f16x8 af = *(const f16x8*)&A2sh[j][(mt * 64 + q * 16 + ((col + q * 4) & 15)) * 8];
                acc[mt][0] = __builtin_amdgcn_mfma_f32_16x16x32_f16(af, bf0, acc[mt][0], 0, 0, 0);
                acc[mt][1] = __builtin_amdgcn_mfma_f32_16x16x32_f16(af, bf1, acc[mt][1], 0, 0, 0);
                acc[mt][2] = __builtin_amdgcn_mfma_f32_16x16x32_f16(af, bf2, acc[mt][2], 0, 0, 0);
                acc[mt][3] = __builtin_amdgcn_mfma_f32_16x16x32_f16(af, bf3, acc[mt][3], 0, 0, 0);
            }

            float s0  = qodd ? uz : 1.f;
            float zx  = qodd ? 0.f : ux;
            float zy  = qodd ? 0.f : uy;
            float exu = qodd ? 1.f : ux;
            float euy = qodd ? 0.f : uy;
            float euz = qodd ? 0.f : uz;
#pragma unroll
            for (int mt = 0; mt < 4; ++mt) {
                float4 bv = *(const float4*)&B2sh[j][mt * 16 + q * 4];
                float t0 = bv.x * vmask, t1 = bv.y * vmask, t2 = bv.z * vmask, t3 = bv.w * vmask;
                ms_p[mt]    += t0 * s0 + t2 * zx + t3 * zy;
                mv_p[mt][0] += t1 * exu;
                mv_p[mt][1] += t1 * euy + t2 * o1;
                mv_p[mt][2] += t1 * euz + t3 * o1;
            }
        }

#pragma unroll
        for (int mt = 0; mt < 4; ++mt) {
            float fs, fv0, fv1, fv2;
            if ((q & 1) == 0) {
                fs  = acc[mt][0][0] + acc[mt][1][2] + acc[mt][2][3];
                fv0 = acc[mt][1][1]; fv1 = acc[mt][2][1]; fv2 = acc[mt][3][1];
            } else {
                fs  = acc[mt][3][0];
                fv0 = acc[mt][0][1]; fv1 = acc[mt][0][2]; fv2 = acc[mt][0][3];
            }
            ms_p[mt]    += fs  * invsb;
            mv_p[mt][0] += fv0 * invsb;
            mv_p[mt][1] += fv1 * invsb;
            mv_p[mt][2] += fv2 * invsb;
        }

        // single xor-16 reduce (q pairs hold complementary cc-streams of same channel)
#pragma unroll
        for (int mt = 0; mt < 4; ++mt) {
            ms_p[mt]    += __shfl_xor(ms_p[mt], 16, 64);
            mv_p[mt][0] += __shfl_xor(mv_p[mt][0], 16, 64);
            mv_p[mt][1] += __shfl_xor(mv_p[mt][1], 16, 64);
            mv_p[mt][2] += __shfl_xor(mv_p[mt][2], 16, 64);
        }

        if ((q & 1) == 0) {
            int nodeD = b * NN + dst;
#pragma unroll
            for (int mt = 0; mt < 4; ++mt) {
                int i2 = (wfh * 4 + mt) * 2 + (q >> 1);
                aggs_out[(size_t)sgrp * 32768 + nodeD * 16 + i2] = ms_p[mt];
                float* vp = aggv_out + (size_t)sgrp * 98304 + nodeD * 48 + i2 * 3;
                vp[0] = mv_p[mt][0]; vp[1] = mv_p[mt][1]; vp[2] = mv_p[mt][2];
            }
        }
    }
}

__global__ __launch_bounds__(256) void k_out(
        const float* __restrict__ aggv, const float* __restrict__ wv,
        const float* __restrict__ wvo, const float* __restrict__ vec,
        const float* __restrict__ pos, float* __restrict__ out) {
    int node0 = blockIdx.x * 4;
    int tid = threadIdx.x;
    int k = tid >> 6, t = tid & 63;
    int node = node0 + k;
    __shared__ float avh[4][48];
    __shared__ float vn[4][48];
    if (t < 48) {
        float a = 0.f;
#pragma unroll
        for (int p = 0; p < 8; ++p) a += aggv[(size_t)p * 98304 + node * 48 + t];
        avh[k][t] = a;
    }
    __syncthreads();
    if (t < 48) {
        int e = t / 3, d = t % 3;
        float acc = 0.f;
#pragma unroll
        for (int c = 0; c < 16; ++c) acc += avh[k][c * 3 + d] * wv[c * 16 + e];
        vn[k][t] = (vec[node * 48 + t] + acc) * wvo[e];
    }
    __syncthreads();
    if (t < 3) {
        float acc = 0.f;
#pragma unroll
        for (int e = 0; e < 16; ++e) acc += vn[k][e * 3 + t];
        out[node * 3 + t] = acc + pos[node * 3 + t];
    }
}

extern "C" void kernel_launch(void* const* d_in, const int* in_sizes, int n_in,
                              void* d_out, int out_size, void* d_ws, size_t ws_size,
                              hipStream_t stream) {
    const float* pos = (const float*)d_in[0];
    const float* v   = (const float*)d_in[1];
    const float* z   = (const float*)d_in[2];
    const float* w_s_in = (const float*)d_in[3];
    const float* w_v_in = (const float*)d_in[4];
    const float* rw1 = (const float*)d_in[5];
    const float* rb1 = (const float*)d_in[6];
    const float* rw2 = (const float*)d_in[7];
    const float* rb2 = (const float*)d_in[8];
    const float* sws = (const float*)d_in[9];
    const float* swv = (const float*)d_in[10];
    const float* wvo = (const float*)d_in[11];
    float* out = (float*)d_out;

    float* wsf = (float*)d_ws;
    float* sA = wsf + SA_OFF;
    float* vA = wsf + VA_OFF;
    float* sB = wsf + SB_OFF;
    float* vB = wsf + VB_OFF;
    float* aggsA = wsf + AGGSA_OFF;
    float* aggvA = wsf + AGGVA_OFF;
    float* aggsB = wsf + AGGSB_OFF;
    float* aggvB = wsf + AGGVB_OFF;
    float* W2R = wsf + W2R_OFF;

    k_w2r<<<192, 256, 0, stream>>>(rw2, W2R);

    // L0: init state -> sA/vA, edge -> aggsA/aggvA
    k_medge<0><<<512, 256, 0, stream>>>(pos, z, v, w_s_in, w_v_in,
                                        sws, swv, sA, vA, sA, vA,
                                        aggsB, aggvB,
                                        W2R, rb2, rw1, rb1,
                                        aggsA, aggvA);
    // L1: update(aggsA)+residual(sA) -> sB/vB, edge -> aggsB/aggvB
    k_medge<1><<<512, 256, 0, stream>>>(pos, z, v, w_s_in, w_v_in,
                                        sws, swv, sA, vA, sB, vB,
                                        aggsA, aggvA,
                                        W2R, rb2 + 1024, rw1 + 32, rb1 + 32,
                                        aggsB, aggvB);
    // L2: update(aggsB)+residual(sB) (no state write), edge -> aggsA/aggvA
    k_medge<2><<<512, 256, 0, stream>>>(pos, z, v, w_s_in, w_v_in,
                                        sws + 256, swv + 256, sB, vB, sA, vA,
                                        aggsB, aggvB,
                                        W2R, rb2 + 2048, rw1 + 64, rb1 + 64,
                                        aggsA, aggvA);
    // out: vec_L1 (vB) + L2 partials (aggvA)
    k_out<<<512, 256, 0, stream>>>(aggvA, swv + 512, wvo, vB, pos, out);
}

// Round 20
// 64.171 us; speedup vs baseline: 1.8406x; 1.0347x over previous
//
#include <hip/hip_runtime.h>

#define NF 16
#define NB 32
#define NN 64
#define EPSV 1e-8f

typedef _Float16 f16x8 __attribute__((ext_vector_type(8)));
typedef _Float16 f16x2 __attribute__((ext_vector_type(2)));
typedef __fp16 fp16x2 __attribute__((ext_vector_type(2)));
typedef float f32x4 __attribute__((ext_vector_type(4)));

// Workspace (float offsets), ping-pong buffers, all overwritten before read:
#define SA_OFF    0
#define VA_OFF    32768
#define SB_OFF    131072
#define VB_OFF    163840
#define AGGSA_OFF 262144
#define AGGVA_OFF 524288
#define AGGSB_OFF 1310720
#define AGGVB_OFF 1572864
#define W2R_OFF   2359296   // 3*65536 floats dense relayout; layers 1,2 built by medge<0>

__device__ __forceinline__ f16x2 cvt_pk(float a, float b) {
    fp16x2 r = __builtin_amdgcn_cvt_pkrtz(a, b);
    return __builtin_bit_cast(f16x2, r);
}

__device__ __forceinline__ f16x8 pack8(f16x2 a, f16x2 b, f16x2 c, f16x2 d) {
    f16x8 r;
    r[0] = a[0]; r[1] = a[1]; r[2] = b[0]; r[3] = b[1];
    r[4] = c[0]; r[5] = c[1]; r[6] = d[0]; r[7] = d[1];
    return r;
}

__device__ __forceinline__ int strm_of(int cc) {
    return (cc == 0) ? 0 : (cc == 1) ? 1 : (cc <= 4) ? 2 : 3;
}

// Merged per-layer kernel: [update from prev partials] + A2/B2 build (LDS) + edge.
// grid 512 = 8 xcd * 4 b * 8 sgrp * 2 fhalf; block owns 8 src nodes, all 64 dst.
// LAYER==0: preloads W2 directly from rw2 (R17 addressing) and cooperatively
//   builds the dense relayout W2R for layers 1,2 (64 coalesced float4/block).
// LAYER>=1: preloads from W2R — every load is a fully-contiguous 1KB burst.
template <int LAYER>
__global__ __launch_bounds__(256, 2) void k_medge(
        const float* __restrict__ pos,
        const float* __restrict__ z, const float* __restrict__ v,
        const float* __restrict__ w_s_in, const float* __restrict__ w_v_in,
        const float* __restrict__ sws_l, const float* __restrict__ swv_l,
        const float* __restrict__ sprev, const float* __restrict__ vprev,
        float* __restrict__ snew, float* __restrict__ vnew,
        const float* __restrict__ aggs_in, const float* __restrict__ aggv_in,
        const float* __restrict__ rw2d, float* __restrict__ W2R,
        const float* __restrict__ b2,
        const float* __restrict__ w1, const float* __restrict__ b1,
        float* __restrict__ aggs_out, float* __restrict__ aggv_out) {
    int blk = blockIdx.x;
    int xcd = blk & 7;
    int t = blk >> 3;                    // 0..63
    int b = xcd * 4 + (t >> 4);
    int rem = t & 15;
    int sgrp = rem >> 1, wfh = rem & 1;
    int tid = threadIdx.x;
    int nbase = b * NN + sgrp * 8;       // this block's 8 src nodes

    __shared__ float pos_sh[NN * 3];
    __shared__ float s_sh[8][16];
    __shared__ float vec_t[3][8][16];    // [d][node][channel]
    __shared__ float aggfull[8][64];
    __shared__ float sigA_sh[8];
    __shared__ int eexp_sh[8];
    __shared__ _Float16 A2sh[8][2048];   // [src][chunk*8], chunk swizzled
    __shared__ float B2sh[8][64];

    if (tid < NN * 3) pos_sh[tid] = pos[(size_t)b * NN * 3 + tid];

    // ---- W2/b2 preload (once, hoisted) ----
    int fh_p = tid & 63, hq8_p = tid >> 6;   // fh 0..63 within half, h-octet/wave
    int fg_p = wfh * 64 + fh_p;
    int i_p = fg_p >> 3, cc_p = fg_p & 7;
    int strm_p = strm_of(cc_p);
    int dd_p = (cc_p <= 1) ? 0 : (cc_p <= 4 ? cc_p - 2 : cc_p - 5);
    float4 wr_all[8][4];
    if (LAYER == 0) {
        // direct from rw2: wave-uniform hq8 => 4 contiguous 512B segments/load
        const float* wp_p = rw2d + (size_t)(hq8_p * 8) * 1024 + strm_p * 256 + i_p * 16;
#pragma unroll
        for (int h8 = 0; h8 < 8; ++h8) {
            const float4* w4 = (const float4*)(wp_p + h8 * 1024);
            wr_all[h8][0] = w4[0]; wr_all[h8][1] = w4[1];
            wr_all[h8][2] = w4[2]; wr_all[h8][3] = w4[3];
        }
        // cooperative W2R build for layers 1,2 (idxq 16384..49151; fh == lane)
        if (tid < 64) {
            int idxq = 16384 + blk * 64 + tid;
            int fh  = idxq & 63;
            int jq  = (idxq >> 6) & 3;
            int h8  = (idxq >> 8) & 7;
            int hq8 = (idxq >> 11) & 3;
            int wfh2 = (idxq >> 13) & 1;
            int l   = idxq >> 14;            // 1 or 2
            int fg = wfh2 * 64 + fh;
            int i2 = fg >> 3, cc2 = fg & 7;
            int h = hq8 * 8 + h8;
            ((float4*)W2R)[idxq] = *(const float4*)(rw2d + (size_t)l * 32768 + h * 1024
                                                    + strm_of(cc2) * 256 + i2 * 16 + jq * 4);
        }
    } else {
        const float* wp_p = W2R + (size_t)(((LAYER * 2 + wfh) * 4 + hq8_p) * 8) * 1024
                            + fh_p * 4;
#pragma unroll
        for (int h8 = 0; h8 < 8; ++h8) {
#pragma unroll
            for (int jq = 0; jq < 4; ++jq) {
                wr_all[h8][jq] = *(const float4*)(wp_p + (h8 * 4 + jq) * 256);
            }
        }
    }
    float4 bw_p[4];
    if (hq8_p == 0) {
        const float4* bp = (const float4*)(b2 + strm_p * 256 + i_p * 16);
        bw_p[0] = bp[0]; bw_p[1] = bp[1]; bw_p[2] = bp[2]; bw_p[3] = bp[3];
    }

    // ---- state phase: init (L0) or update from prev partials (L1,L2) ----
    if (LAYER == 0) {
        for (int it = tid; it < 512; it += 256) {
            int k = it >> 6, ch = it & 63;
            int node = nbase + k;
            if (ch < 16) {
                float val = z[node] * w_s_in[ch];
                s_sh[k][ch] = val;
                if (wfh == 0) snew[node * 16 + ch] = val;
            } else {
                int q = ch - 16, e = q / 3, d = q % 3;
                float val = v[node * 3 + d] * w_v_in[e];
                vec_t[d][k][e] = val;
                if (wfh == 0) vnew[node * 48 + q] = val;
            }
        }
    } else {
        for (int it = tid; it < 512; it += 256) {
            int k = it >> 6, ch = it & 63;
            int node = nbase + k;
            float a = 0.f;
            if (ch < 16) {
#pragma unroll
                for (int p = 0; p < 8; ++p) a += aggs_in[(size_t)p * 32768 + node * 16 + ch];
            } else {
#pragma unroll
                for (int p = 0; p < 8; ++p) a += aggv_in[(size_t)p * 98304 + node * 48 + (ch - 16)];
            }
            aggfull[k][ch] = a;
        }
        __syncthreads();
        for (int it = tid; it < 512; it += 256) {
            int k = it >> 6, ch = it & 63;
            int node = nbase + k;
            if (ch < 16) {
                float acc = 0.f;
#pragma unroll
                for (int c = 0; c < 16; ++c) acc += aggfull[k][c] * sws_l[c * 16 + ch];
                float val = sprev[node * 16 + ch] + fmaxf(acc, 0.f);
                s_sh[k][ch] = val;
                if (LAYER == 1 && wfh == 0) snew[node * 16 + ch] = val;
            } else {
                int q = ch - 16, e = q / 3, d = q % 3;
                float acc = 0.f;
#pragma unroll
                for (int c = 0; c < 16; ++c) acc += aggfull[k][16 + c * 3 + d] * swv_l[c * 16 + e];
                float val = vprev[node * 48 + q] + acc;
                vec_t[d][k][e] = val;
                if (LAYER == 1 && wfh == 0) vnew[node * 48 + q] = val;
            }
        }
    }
    __syncthreads();

    // ---- per-node scale exponent (block-local) ----
    if (tid < 8) {
        float m = 0.f;
#pragma unroll
        for (int j = 0; j < 16; ++j) m = fmaxf(m, fabsf(s_sh[tid][j]));
#pragma unroll
        for (int d = 0; d < 3; ++d)
#pragma unroll
            for (int e = 0; e < 16; ++e) m = fmaxf(m, fabsf(vec_t[d][tid][e]));
        unsigned mb = __float_as_uint(m);
        int ex = (int)((mb >> 23) & 0xFF);
        eexp_sh[tid] = ex - 126;
        sigA_sh[tid] = __uint_as_float((unsigned)(253 - ex) << 23);  // 2^(126-ex)
    }
    __syncthreads();

    // ---- pre phase: single k2 sweep; W2 already in registers; same stores ----
    {
        int mt = fh_p >> 4, colw = fh_p & 15;
        int chunk = mt * 64 + hq8_p * 16 + ((colw + hq8_p * 4) & 15);  // bank swizzle
#pragma unroll
        for (int k2 = 0; k2 < 8; ++k2) {
            const float* srcp = (strm_p <= 1) ? &s_sh[k2][0] : &vec_t[dd_p][k2][0];
            const float4* f4 = (const float4*)srcp;
            float4 f0 = f4[0], f1 = f4[1], f2 = f4[2], f3 = f4[3];
            float sA = sigA_sh[k2];
            f16x8 st;
#pragma unroll
            for (int h8 = 0; h8 < 8; ++h8) {
                float4 a0 = wr_all[h8][0], a1 = wr_all[h8][1];
                float4 a2 = wr_all[h8][2], a3 = wr_all[h8][3];
                float acc = a0.x * f0.x + a0.y * f0.y + a0.z * f0.z + a0.w * f0.w
                          + a1.x * f1.x + a1.y * f1.y + a1.z * f1.z + a1.w * f1.w
                          + a2.x * f2.x + a2.y * f2.y + a2.z * f2.z + a2.w * f2.w
                          + a3.x * f3.x + a3.y * f3.y + a3.z * f3.z + a3.w * f3.w;
                st[h8] = (_Float16)(acc * sA);
            }
            *(f16x8*)&A2sh[k2][chunk * 8] = st;
            if (hq8_p == 0) {
                float accb = bw_p[0].x * f0.x + bw_p[0].y * f0.y + bw_p[0].z * f0.z + bw_p[0].w * f0.w
                           + bw_p[1].x * f1.x + bw_p[1].y * f1.y + bw_p[1].z * f1.z + bw_p[1].w * f1.w
                           + bw_p[2].x * f2.x + bw_p[2].y * f2.y + bw_p[2].z * f2.z + bw_p[2].w * f2.w
                           + bw_p[3].x * f3.x + bw_p[3].y * f3.y + bw_p[3].z * f3.z + bw_p[3].w * f3.w;
                B2sh[k2][fh_p] = accb;   // unscaled
            }
        }
    }
    __syncthreads();

    // ---- edge phase: 4 waves x 16 dst cols, MFMA over 8 srcs from LDS ----
    {
        int wd = tid >> 6;
        int lane = tid & 63;
        int q = lane >> 4, col = lane & 15;
        int dst = wd * 16 + col;
        float qodd = (float)(q & 1);
        float o1 = qodd;

        float pdx = pos_sh[dst * 3 + 0], pdy = pos_sh[dst * 3 + 1], pdz = pos_sh[dst * 3 + 2];
        float w1r[8], b1r[8];
#pragma unroll
        for (int j = 0; j < 8; ++j) { w1r[j] = w1[q * 8 + j]; b1r[j] = b1[q * 8 + j]; }

        int es[8], eblk = -10000;
#pragma unroll
        for (int j = 0; j < 8; ++j) {
            es[j] = eexp_sh[j];
            eblk = es[j] > eblk ? es[j] : eblk;
        }
        float invsb = __uint_as_float((unsigned)(127 + eblk) << 23);  // 2^eblk

        f32x4 acc[4][4];
#pragma unroll
        for (int mt = 0; mt < 4; ++mt)
#pragma unroll
            for (int u = 0; u < 4; ++u) acc[mt][u] = (f32x4){0.f, 0.f, 0.f, 0.f};
        float ms_p[4] = {0.f, 0.f, 0.f, 0.f};
        float mv_p[4][3];
#pragma unroll
        for (int mt = 0; mt < 4; ++mt) { mv_p[mt][0] = 0.f; mv_p[mt][1] = 0.f; mv_p[mt][2] = 0.f; }

        for (int j = 0; j < 8; ++j) {
            int src = sgrp * 8 + j;
            float psx = pos_sh[src * 3 + 0];
            float psy = pos_sh[src * 3 + 1];
            float psz = pos_sh[src * 3 + 2];
            float dx = pdx - psx, dy = pdy - psy, dz = pdz - psz;
            float r = __builtin_amdgcn_sqrtf(dx * dx + dy * dy + dz * dz);
            float inv = __builtin_amdgcn_rcpf(r + EPSV);
            float ux = dx * inv, uy = dy * inv, uz = dz * inv;
            float vmask = (dst == src) ? 0.f : 1.f;

            int dEx = es[j] - eblk;
            float sc2 = (dEx < -120) ? 0.f : __uint_as_float((unsigned)(127 + dEx) << 23);
            float scl = sc2 * vmask;

            f16x2 ux2 = {(_Float16)ux, (_Float16)ux};
            f16x2 uy2 = {(_Float16)uy, (_Float16)uy};
            f16x2 uz2 = {(_Float16)uz, (_Float16)uz};
            f16x2 p0[4], p1[4], p2[4], p3[4];
#pragma unroll
            for (int jp = 0; jp < 4; ++jp) {
                float h0 = fmaxf(fmaf(r, w1r[2 * jp],     b1r[2 * jp]),     0.f) * scl;
                float h1 = fmaxf(fmaf(r, w1r[2 * jp + 1], b1r[2 * jp + 1]), 0.f) * scl;
                p0[jp] = cvt_pk(h0, h1);
                p1[jp] = p0[jp] * ux2;
                p2[jp] = p0[jp] * uy2;
                p3[jp] = p0[jp] * uz2;
            }
            f16x8 bf0 = pack8(p0[0], p0[1], p0[2], p0[3]);
            f16x8 bf1 = pack8(p1[0], p1[1], p1[2], p1[3]);
            f16x8 bf2 = pack8(p2[0], p2[1], p2[2], p2[3]);
            f16x8 bf3 = pack8(p3[0], p3[1], p3[2], p3[3]);

#pragma unroll
            for (int mt = 0; mt < 4; ++mt) {
                f16x8 af = *(const f16x8*)&A2sh[j][(mt * 64 + q * 16 + ((col + q * 4) & 15)) * 8];
                acc[mt][0] = __builtin_amdgcn_mfma_f32_16x16x32_f16(af, bf0, acc[mt][0], 0, 0, 0);
                acc[mt][1] = __builtin_amdgcn_mfma_f32_16x16x32_f16(af, bf1, acc[mt][1], 0, 0, 0);
                acc[mt][2] = __builtin_amdgcn_mfma_f32_16x16x32_f16(af, bf2, acc[mt][2], 0, 0, 0);
                acc[mt][3] = __builtin_amdgcn_mfma_f32_16x16x32_f16(af, bf3, acc[mt][3], 0, 0, 0);
            }

            float s0  = qodd ? uz : 1.f;
            float zx  = qodd ? 0.f : ux;
            float zy  = qodd ? 0.f : uy;
            float exu = qodd ? 1.f : ux;
            float euy = qodd ? 0.f : uy;
            float euz = qodd ? 0.f : uz;
#pragma unroll
            for (int mt = 0; mt < 4; ++mt) {
                float4 bv = *(const float4*)&B2sh[j][mt * 16 + q * 4];
                float t0 = bv.x * vmask, t1 = bv.y * vmask, t2 = bv.z * vmask, t3 = bv.w * vmask;
                ms_p[mt]    += t0 * s0 + t2 * zx + t3 * zy;
                mv_p[mt][0] += t1 * exu;
                mv_p[mt][1] += t1 * euy + t2 * o1;
                mv_p[mt][2] += t1 * euz + t3 * o1;
            }
        }

#pragma unroll
        for (int mt = 0; mt < 4; ++mt) {
            float fs, fv0, fv1, fv2;
            if ((q & 1) == 0) {
                fs  = acc[mt][0][0] + acc[mt][1][2] + acc[mt][2][3];
                fv0 = acc[mt][1][1]; fv1 = acc[mt][2][1]; fv2 = acc[mt][3][1];
            } else {
                fs  = acc[mt][3][0];
                fv0 = acc[mt][0][1]; fv1 = acc[mt][0][2]; fv2 = acc[mt][0][3];
            }
            ms_p[mt]    += fs  * invsb;
            mv_p[mt][0] += fv0 * invsb;
            mv_p[mt][1] += fv1 * invsb;
            mv_p[mt][2] += fv2 * invsb;
        }

        // single xor-16 reduce (q pairs hold complementary cc-streams of same channel)
#pragma unroll
        for (int mt = 0; mt < 4; ++mt) {
            ms_p[mt]    += __shfl_xor(ms_p[mt], 16, 64);
            mv_p[mt][0] += __shfl_xor(mv_p[mt][0], 16, 64);
            mv_p[mt][1] += __shfl_xor(mv_p[mt][1], 16, 64);
            mv_p[mt][2] += __shfl_xor(mv_p[mt][2], 16, 64);
        }

        if ((q & 1) == 0) {
            int nodeD = b * NN + dst;
#pragma unroll
            for (int mt = 0; mt < 4; ++mt) {
                int i2 = (wfh * 4 + mt) * 2 + (q >> 1);
                aggs_out[(size_t)sgrp * 32768 + nodeD * 16 + i2] = ms_p[mt];
                float* vp = aggv_out + (size_t)sgrp * 98304 + nodeD * 48 + i2 * 3;
                vp[0] = mv_p[mt][0]; vp[1] = mv_p[mt][1]; vp[2] = mv_p[mt][2];
            }
        }
    }
}

__global__ __launch_bounds__(256) void k_out(
        const float* __restrict__ aggv, const float* __restrict__ wv,
        const float* __restrict__ wvo, const float* __restrict__ vec,
        const float* __restrict__ pos, float* __restrict__ out) {
    int node0 = blockIdx.x * 4;
    int tid = threadIdx.x;
    int k = tid >> 6, t = tid & 63;
    int node = node0 + k;
    __shared__ float avh[4][48];
    __shared__ float vn[4][48];
    if (t < 48) {
        float a = 0.f;
#pragma unroll
        for (int p = 0; p < 8; ++p) a += aggv[(size_t)p * 98304 + node * 48 + t];
        avh[k][t] = a;
    }
    __syncthreads();
    if (t < 48) {
        int e = t / 3, d = t % 3;
        float acc = 0.f;
#pragma unroll
        for (int c = 0; c < 16; ++c) acc += avh[k][c * 3 + d] * wv[c * 16 + e];
        vn[k][t] = (vec[node * 48 + t] + acc) * wvo[e];
    }
    __syncthreads();
    if (t < 3) {
        float acc = 0.f;
#pragma unroll
        for (int e = 0; e < 16; ++e) acc += vn[k][e * 3 + t];
        out[node * 3 + t] = acc + pos[node * 3 + t];
    }
}

extern "C" void kernel_launch(void* const* d_in, const int* in_sizes, int n_in,
                              void* d_out, int out_size, void* d_ws, size_t ws_size,
                              hipStream_t stream) {
    const float* pos = (const float*)d_in[0];
    const float* v   = (const float*)d_in[1];
    const float* z   = (const float*)d_in[2];
    const float* w_s_in = (const float*)d_in[3];
    const float* w_v_in = (const float*)d_in[4];
    const float* rw1 = (const float*)d_in[5];
    const float* rb1 = (const float*)d_in[6];
    const float* rw2 = (const float*)d_in[7];
    const float* rb2 = (const float*)d_in[8];
    const float* sws = (const float*)d_in[9];
    const float* swv = (const float*)d_in[10];
    const float* wvo = (const float*)d_in[11];
    float* out = (float*)d_out;

    float* wsf = (float*)d_ws;
    float* sA = wsf + SA_OFF;
    float* vA = wsf + VA_OFF;
    float* sB = wsf + SB_OFF;
    float* vB = wsf + VB_OFF;
    float* aggsA = wsf + AGGSA_OFF;
    float* aggvA = wsf + AGGVA_OFF;
    float* aggsB = wsf + AGGSB_OFF;
    float* aggvB = wsf + AGGVB_OFF;
    float* W2R = wsf + W2R_OFF;

    // L0: init state -> sA/vA, edge -> aggsA/aggvA; builds W2R for layers 1,2
    k_medge<0><<<512, 256, 0, stream>>>(pos, z, v, w_s_in, w_v_in,
                                        sws, swv, sA, vA, sA, vA,
                                        aggsB, aggvB,
                                        rw2, W2R, rb2, rw1, rb1,
                                        aggsA, aggvA);
    // L1: update(aggsA)+residual(sA) -> sB/vB, edge -> aggsB/aggvB
    k_medge<1><<<512, 256, 0, stream>>>(pos, z, v, w_s_in, w_v_in,
                                        sws, swv, sA, vA, sB, vB,
                                        aggsA, aggvA,
                                        rw2, W2R, rb2 + 1024, rw1 + 32, rb1 + 32,
                                        aggsB, aggvB);
    // L2: update(aggsB)+residual(sB) (no state write), edge -> aggsA/aggvA
    k_medge<2><<<512, 256, 0, stream>>>(pos, z, v, w_s_in, w_v_in,
                                        sws + 256, swv + 256, sB, vB, sA, vA,
                                        aggsB, aggvB,
                                        rw2, W2R, rb2 + 2048, rw1 + 64, rb1 + 64,
                                        aggsA, aggvA);
    // out: vec_L1 (vB) + L2 partials (aggvA)
    k_out<<<512, 256, 0, stream>>>(aggvA, swv + 512, wvo, vB, pos, out);
}

// Round 21
// 62.707 us; speedup vs baseline: 1.8836x; 1.0234x over previous
//
#include <hip/hip_runtime.h>

#define NF 16
#define NB 32
#define NN 64
#define EPSV 1e-8f

typedef _Float16 f16x8 __attribute__((ext_vector_type(8)));
typedef _Float16 f16x2 __attribute__((ext_vector_type(2)));
typedef __fp16 fp16x2 __attribute__((ext_vector_type(2)));
typedef float f32x4 __attribute__((ext_vector_type(4)));

// Workspace (float offsets), ping-pong buffers, all overwritten before read:
#define SA_OFF    0
#define VA_OFF    32768
#define SB_OFF    131072
#define VB_OFF    163840
#define AGGSA_OFF 262144
#define AGGVA_OFF 524288
#define AGGSB_OFF 1310720
#define AGGVB_OFF 1572864
#define W2R_OFF   2359296   // 3*65536 floats dense relayout; layers 1,2 built by medge<0>

__device__ __forceinline__ f16x2 cvt_pk(float a, float b) {
    fp16x2 r = __builtin_amdgcn_cvt_pkrtz(a, b);
    return __builtin_bit_cast(f16x2, r);
}

__device__ __forceinline__ f16x8 pack8(f16x2 a, f16x2 b, f16x2 c, f16x2 d) {
    f16x8 r;
    r[0] = a[0]; r[1] = a[1]; r[2] = b[0]; r[3] = b[1];
    r[4] = c[0]; r[5] = c[1]; r[6] = d[0]; r[7] = d[1];
    return r;
}

__device__ __forceinline__ int strm_of(int cc) {
    return (cc == 0) ? 0 : (cc == 1) ? 1 : (cc <= 4) ? 2 : 3;
}

// Merged per-layer kernel: [update from prev partials] + A2/B2 build (LDS) + edge.
// grid 512 = 8 xcd * 4 b * 8 sgrp * 2 fhalf; block owns 8 src nodes, all 64 dst.
// LAYER==0: preloads W2 directly from rw2 and builds the dense relayout W2R.
// LAYER>=1: preloads from W2R (fully-contiguous 1KB bursts).
template <int LAYER>
__global__ __launch_bounds__(256, 2) void k_medge(
        const float* __restrict__ pos,
        const float* __restrict__ z, const float* __restrict__ v,
        const float* __restrict__ w_s_in, const float* __restrict__ w_v_in,
        const float* __restrict__ sws_l, const float* __restrict__ swv_l,
        const float* __restrict__ sprev, const float* __restrict__ vprev,
        float* __restrict__ snew, float* __restrict__ vnew,
        const float* __restrict__ aggs_in, const float* __restrict__ aggv_in,
        const float* __restrict__ rw2d, float* __restrict__ W2R,
        const float* __restrict__ b2,
        const float* __restrict__ w1, const float* __restrict__ b1,
        float* __restrict__ aggs_out, float* __restrict__ aggv_out) {
    int blk = blockIdx.x;
    int xcd = blk & 7;
    int t = blk >> 3;                    // 0..63
    int b = xcd * 4 + (t >> 4);
    int rem = t & 15;
    int sgrp = rem >> 1, wfh = rem & 1;
    int tid = threadIdx.x;
    int nbase = b * NN + sgrp * 8;       // this block's 8 src nodes

    __shared__ float pos_sh[NN * 3];
    __shared__ float s_sh[8][16];
    __shared__ float vec_t[3][8][16];    // [d][node][channel]
    __shared__ float aggfull[8][64];
    __shared__ float sigA_sh[8];
    __shared__ int eexp_sh[8];
    __shared__ _Float16 A2sh[8][2048];   // [src][chunk*8], chunk swizzled
    __shared__ float B2sh[8][64];

    if (tid < NN * 3) pos_sh[tid] = pos[(size_t)b * NN * 3 + tid];

    // ---- W2/b2 preload (once, hoisted) ----
    int fh_p = tid & 63, hq8_p = tid >> 6;   // fh 0..63 within half, h-octet/wave
    int fg_p = wfh * 64 + fh_p;
    int i_p = fg_p >> 3, cc_p = fg_p & 7;
    int strm_p = strm_of(cc_p);
    int dd_p = (cc_p <= 1) ? 0 : (cc_p <= 4 ? cc_p - 2 : cc_p - 5);
    float4 wr_all[8][4];
    if (LAYER == 0) {
        const float* wp_p = rw2d + (size_t)(hq8_p * 8) * 1024 + strm_p * 256 + i_p * 16;
#pragma unroll
        for (int h8 = 0; h8 < 8; ++h8) {
            const float4* w4 = (const float4*)(wp_p + h8 * 1024);
            wr_all[h8][0] = w4[0]; wr_all[h8][1] = w4[1];
            wr_all[h8][2] = w4[2]; wr_all[h8][3] = w4[3];
        }
        // cooperative W2R build for layers 1,2 (idxq 16384..49151)
        if (tid < 64) {
            int idxq = 16384 + blk * 64 + tid;
            int fh  = idxq & 63;
            int jq  = (idxq >> 6) & 3;
            int h8  = (idxq >> 8) & 7;
            int hq8 = (idxq >> 11) & 3;
            int wfh2 = (idxq >> 13) & 1;
            int l   = idxq >> 14;            // 1 or 2
            int fg = wfh2 * 64 + fh;
            int i2 = fg >> 3, cc2 = fg & 7;
            int h = hq8 * 8 + h8;
            ((float4*)W2R)[idxq] = *(const float4*)(rw2d + (size_t)l * 32768 + h * 1024
                                                    + strm_of(cc2) * 256 + i2 * 16 + jq * 4);
        }
    } else {
        const float* wp_p = W2R + (size_t)(((LAYER * 2 + wfh) * 4 + hq8_p) * 8) * 1024
                            + fh_p * 4;
#pragma unroll
        for (int h8 = 0; h8 < 8; ++h8) {
#pragma unroll
            for (int jq = 0; jq < 4; ++jq) {
                wr_all[h8][jq] = *(const float4*)(wp_p + (h8 * 4 + jq) * 256);
            }
        }
    }
    float4 bw_p[4];
    if (hq8_p == 0) {
        const float4* bp = (const float4*)(b2 + strm_p * 256 + i_p * 16);
        bw_p[0] = bp[0]; bw_p[1] = bp[1]; bw_p[2] = bp[2]; bw_p[3] = bp[3];
    }

    // ---- state phase: init (L0) or update from prev partials (L1,L2) ----
    if (LAYER == 0) {
        for (int it = tid; it < 512; it += 256) {
            int k = it >> 6, ch = it & 63;
            int node = nbase + k;
            if (ch < 16) {
                float val = z[node] * w_s_in[ch];
                s_sh[k][ch] = val;
                if (wfh == 0) snew[node * 16 + ch] = val;
            } else {
                int q = ch - 16, e = q / 3, d = q % 3;
                float val = v[node * 3 + d] * w_v_in[e];
                vec_t[d][k][e] = val;
                if (wfh == 0) vnew[node * 48 + q] = val;
            }
        }
    } else {
        // residual loads hoisted before the barrier: overlap with agg reduce
        float resid[2];
        {
            int ii = 0;
            for (int it = tid; it < 512; it += 256, ++ii) {
                int k = it >> 6, ch = it & 63;
                int node = nbase + k;
                float a = 0.f;
                if (ch < 16) {
#pragma unroll
                    for (int p = 0; p < 8; ++p) a += aggs_in[(size_t)p * 32768 + node * 16 + ch];
                    resid[ii] = sprev[node * 16 + ch];
                } else {
#pragma unroll
                    for (int p = 0; p < 8; ++p) a += aggv_in[(size_t)p * 98304 + node * 48 + (ch - 16)];
                    resid[ii] = vprev[node * 48 + (ch - 16)];
                }
                aggfull[k][ch] = a;
            }
        }
        __syncthreads();
        {
            int ii = 0;
            for (int it = tid; it < 512; it += 256, ++ii) {
                int k = it >> 6, ch = it & 63;
                int node = nbase + k;
                if (ch < 16) {
                    float acc = 0.f;
#pragma unroll
                    for (int c = 0; c < 16; ++c) acc += aggfull[k][c] * sws_l[c * 16 + ch];
                    float val = resid[ii] + fmaxf(acc, 0.f);
                    s_sh[k][ch] = val;
                    if (LAYER == 1 && wfh == 0) snew[node * 16 + ch] = val;
                } else {
                    int q = ch - 16, e = q / 3, d = q % 3;
                    float acc = 0.f;
#pragma unroll
                    for (int c = 0; c < 16; ++c) acc += aggfull[k][16 + c * 3 + d] * swv_l[c * 16 + e];
                    float val = resid[ii] + acc;
                    vec_t[d][k][e] = val;
                    if (LAYER == 1 && wfh == 0) vnew[node * 48 + q] = val;
                }
            }
        }
    }
    __syncthreads();

    // ---- per-node scale exponent: 8 threads/node + shfl reduce ----
    if (tid < 64) {
        int nk = tid >> 3, sub = tid & 7;
        float m = 0.f;
#pragma unroll
        for (int e = 0; e < 8; ++e) {
            int idx = sub * 8 + e;
            float x = (idx < 16) ? s_sh[nk][idx] : vec_t[(idx - 16) >> 4][nk][(idx - 16) & 15];
            m = fmaxf(m, fabsf(x));
        }
        m = fmaxf(m, __shfl_xor(m, 1));
        m = fmaxf(m, __shfl_xor(m, 2));
        m = fmaxf(m, __shfl_xor(m, 4));
        if (sub == 0) {
            unsigned mb = __float_as_uint(m);
            int ex = (int)((mb >> 23) & 0xFF);
            eexp_sh[nk] = ex - 126;
            sigA_sh[nk] = __uint_as_float((unsigned)(253 - ex) << 23);  // 2^(126-ex)
        }
    }
    __syncthreads();

    // ---- pre phase: single k2 sweep; W2 already in registers; same stores ----
    {
        int mt = fh_p >> 4, colw = fh_p & 15;
        int chunk = mt * 64 + hq8_p * 16 + ((colw + hq8_p * 4) & 15);  // bank swizzle
#pragma unroll
        for (int k2 = 0; k2 < 8; ++k2) {
            const float* srcp = (strm_p <= 1) ? &s_sh[k2][0] : &vec_t[dd_p][k2][0];
            const float4* f4 = (const float4*)srcp;
            float4 f0 = f4[0], f1 = f4[1], f2 = f4[2], f3 = f4[3];
            float sA = sigA_sh[k2];
            f16x8 st;
#pragma unroll
            for (int h8 = 0; h8 < 8; ++h8) {
                float4 a0 = wr_all[h8][0], a1 = wr_all[h8][1];
                float4 a2 = wr_all[h8][2], a3 = wr_all[h8][3];
                float acc = a0.x * f0.x + a0.y * f0.y + a0.z * f0.z + a0.w * f0.w
                          + a1.x * f1.x + a1.y * f1.y + a1.z * f1.z + a1.w * f1.w
                          + a2.x * f2.x + a2.y * f2.y + a2.z * f2.z + a2.w * f2.w
                          + a3.x * f3.x + a3.y * f3.y + a3.z * f3.z + a3.w * f3.w;
                st[h8] = (_Float16)(acc * sA);
            }
            *(f16x8*)&A2sh[k2][chunk * 8] = st;
            if (hq8_p == 0) {
                float accb = bw_p[0].x * f0.x + bw_p[0].y * f0.y + bw_p[0].z * f0.z + bw_p[0].w * f0.w
                           + bw_p[1].x * f1.x + bw_p[1].y * f1.y + bw_p[1].z * f1.z + bw_p[1].w * f1.w
                           + bw_p[2].x * f2.x + bw_p[2].y * f2.y + bw_p[2].z * f2.z + bw_p[2].w * f2.w
                           + bw_p[3].x * f3.x + bw_p[3].y * f3.y + bw_p[3].z * f3.z + bw_p[3].w * f3.w;
                B2sh[k2][fh_p] = accb;   // unscaled
            }
        }
    }
    __syncthreads();

    // ---- edge phase: 4 waves x 16 dst cols, MFMA over 8 srcs from LDS ----
    {
        int wd = tid >> 6;
        int lane = tid & 63;
        int q = lane >> 4, col = lane & 15;
        int dst = wd * 16 + col;
        float qodd = (float)(q & 1);
        float o1 = qodd;

        float pdx = pos_sh[dst * 3 + 0], pdy = pos_sh[dst * 3 + 1], pdz = pos_sh[dst * 3 + 2];
        float w1r[8], b1r[8];
#pragma unroll
        for (int j = 0; j < 8; ++j) { w1r[j] = w1[q * 8 + j]; b1r[j] = b1[q * 8 + j]; }

        int es[8], eblk = -10000;
#pragma unroll
        for (int j = 0; j < 8; ++j) {
            es[j] = eexp_sh[j];
            eblk = es[j] > eblk ? es[j] : eblk;
        }
        float invsb = __uint_as_float((unsigned)(127 + eblk) << 23);  // 2^eblk

        f32x4 acc[4][4];
#pragma unroll
        for (int mt = 0; mt < 4; ++mt)
#pragma unroll
            for (int u = 0; u < 4; ++u) acc[mt][u] = (f32x4){0.f, 0.f, 0.f, 0.f};
        float ms_p[4] = {0.f, 0.f, 0.f, 0.f};
        float mv_p[4][3];
#pragma unroll
        for (int mt = 0; mt < 4; ++mt) { mv_p[mt][0] = 0.f; mv_p[mt][1] = 0.f; mv_p[mt][2] = 0.f; }

        for (int j = 0; j < 8; ++j) {
            int src = sgrp * 8 + j;
            float psx = pos_sh[src * 3 + 0];
            float psy = pos_sh[src * 3 + 1];
            float psz = pos_sh[src * 3 + 2];
            float dx = pdx - psx, dy = pdy - psy, dz = pdz - psz;
            float r = __builtin_amdgcn_sqrtf(dx * dx + dy * dy + dz * dz);
            float inv = __builtin_amdgcn_rcpf(r + EPSV);
            float ux = dx * inv, uy = dy * inv, uz = dz * inv;
            float vmask = (dst == src) ? 0.f : 1.f;

            int dEx = es[j] - eblk;
            float sc2 = (dEx < -120) ? 0.f : __uint_as_float((unsigned)(127 + dEx) << 23);
            float scl = sc2 * vmask;

            f16x2 ux2 = {(_Float16)ux, (_Float16)ux};
            f16x2 uy2 = {(_Float16)uy, (_Float16)uy};
            f16x2 uz2 = {(_Float16)uz, (_Float16)uz};
            f16x2 p0[4], p1[4], p2[4], p3[4];
#pragma unroll
            for (int jp = 0; jp < 4; ++jp) {
                float h0 = fmaxf(fmaf(r, w1r[2 * jp],     b1r[2 * jp]),     0.f) * scl;
                float h1 = fmaxf(fmaf(r, w1r[2 * jp + 1], b1r[2 * jp + 1]), 0.f) * scl;
                p0[jp] = cvt_pk(h0, h1);
                p1[jp] = p0[jp] * ux2;
                p2[jp] = p0[jp] * uy2;
                p3[jp] = p0[jp] * uz2;
            }
            f16x8 bf0 = pack8(p0[0], p0[1], p0[2], p0[3]);
            f16x8 bf1 = pack8(p1[0], p1[1], p1[2], p1[3]);
            f16x8 bf2 = pack8(p2[0], p2[1], p2[2], p2[3]);
            f16x8 bf3 = pack8(p3[0], p3[1], p3[2], p3[3]);

#pragma unroll
            for (int mt = 0; mt < 4; ++mt) {
                f16x8 af = *(const f16x8*)&A2sh[j][(mt * 64 + q * 16 + ((col + q * 4) & 15)) * 8];
                acc[mt][0] = __builtin_amdgcn_mfma_f32_16x16x32_f16(af, bf0, acc[mt][0], 0, 0, 0);
                acc[mt][1] = __builtin_amdgcn_mfma_f32_16x16x32_f16(af, bf1, acc[mt][1], 0, 0, 0);
                acc[mt][2] = __builtin_amdgcn_mfma_f32_16x16x32_f16(af, bf2, acc[mt][2], 0, 0, 0);
                acc[mt][3] = __builtin_amdgcn_mfma_f32_16x16x32_f16(af, bf3, acc[mt][3], 0, 0, 0);
            }

            float s0  = qodd ? uz : 1.f;
            float zx  = qodd ? 0.f : ux;
            float zy  = qodd ? 0.f : uy;
            float exu = qodd ? 1.f : ux;
            float euy = qodd ? 0.f : uy;
            float euz = qodd ? 0.f : uz;
#pragma unroll
            for (int mt = 0; mt < 4; ++mt) {
                float4 bv = *(const float4*)&B2sh[j][mt * 16 + q * 4];
                float t0 = bv.x * vmask, t1 = bv.y * vmask, t2 = bv.z * vmask, t3 = bv.w * vmask;
                ms_p[mt]    += t0 * s0 + t2 * zx + t3 * zy;
                mv_p[mt][0] += t1 * exu;
                mv_p[mt][1] += t1 * euy + t2 * o1;
                mv_p[mt][2] += t1 * euz + t3 * o1;
            }
        }

#pragma unroll
        for (int mt = 0; mt < 4; ++mt) {
            float fs, fv0, fv1, fv2;
            if ((q & 1) == 0) {
                fs  = acc[mt][0][0] + acc[mt][1][2] + acc[mt][2][3];
                fv0 = acc[mt][1][1]; fv1 = acc[mt][2][1]; fv2 = acc[mt][3][1];
            } else {
                fs  = acc[mt][3][0];
                fv0 = acc[mt][0][1]; fv1 = acc[mt][0][2]; fv2 = acc[mt][0][3];
            }
            ms_p[mt]    += fs  * invsb;
            mv_p[mt][0] += fv0 * invsb;
            mv_p[mt][1] += fv1 * invsb;
            mv_p[mt][2] += fv2 * invsb;
        }

        // single xor-16 reduce (q pairs hold complementary cc-streams of same channel)
#pragma unroll
        for (int mt = 0; mt < 4; ++mt) {
            ms_p[mt]    += __shfl_xor(ms_p[mt], 16, 64);
            mv_p[mt][0] += __shfl_xor(mv_p[mt][0], 16, 64);
            mv_p[mt][1] += __shfl_xor(mv_p[mt][1], 16, 64);
            mv_p[mt][2] += __shfl_xor(mv_p[mt][2], 16, 64);
        }

        if ((q & 1) == 0) {
            int nodeD = b * NN + dst;
#pragma unroll
            for (int mt = 0; mt < 4; ++mt) {
                int i2 = (wfh * 4 + mt) * 2 + (q >> 1);
                aggs_out[(size_t)sgrp * 32768 + nodeD * 16 + i2] = ms_p[mt];
                float* vp = aggv_out + (size_t)sgrp * 98304 + nodeD * 48 + i2 * 3;
                vp[0] = mv_p[mt][0]; vp[1] = mv_p[mt][1]; vp[2] = mv_p[mt][2];
            }
        }
    }
}

__global__ __launch_bounds__(256) void k_out(
        const float* __restrict__ aggv, const float* __restrict__ wv,
        const float* __restrict__ wvo, const float* __restrict__ vec,
        const float* __restrict__ pos, float* __restrict__ out) {
    int node0 = blockIdx.x * 4;
    int tid = threadIdx.x;
    int k = tid >> 6, t = tid & 63;
    int node = node0 + k;
    __shared__ float avh[4][48];
    __shared__ float vn[4][48];
    if (t < 48) {
        float a = 0.f;
#pragma unroll
        for (int p = 0; p < 8; ++p) a += aggv[(size_t)p * 98304 + node * 48 + t];
        avh[k][t] = a;
    }
    __syncthreads();
    if (t < 48) {
        int e = t / 3, d = t % 3;
        float acc = 0.f;
#pragma unroll
        for (int c = 0; c < 16; ++c) acc += avh[k][c * 3 + d] * wv[c * 16 + e];
        vn[k][t] = (vec[node * 48 + t] + acc) * wvo[e];
    }
    __syncthreads();
    if (t < 3) {
        float acc = 0.f;
#pragma unroll
        for (int e = 0; e < 16; ++e) acc += vn[k][e * 3 + t];
        out[node * 3 + t] = acc + pos[node * 3 + t];
    }
}

extern "C" void kernel_launch(void* const* d_in, const int* in_sizes, int n_in,
                              void* d_out, int out_size, void* d_ws, size_t ws_size,
                              hipStream_t stream) {
    const float* pos = (const float*)d_in[0];
    const float* v   = (const float*)d_in[1];
    const float* z   = (const float*)d_in[2];
    const float* w_s_in = (const float*)d_in[3];
    const float* w_v_in = (const float*)d_in[4];
    const float* rw1 = (const float*)d_in[5];
    const float* rb1 = (const float*)d_in[6];
    const float* rw2 = (const float*)d_in[7];
    const float* rb2 = (const float*)d_in[8];
    const float* sws = (const float*)d_in[9];
    const float* swv = (const float*)d_in[10];
    const float* wvo = (const float*)d_in[11];
    float* out = (float*)d_out;

    float* wsf = (float*)d_ws;
    float* sA = wsf + SA_OFF;
    float* vA = wsf + VA_OFF;
    float* sB = wsf + SB_OFF;
    float* vB = wsf + VB_OFF;
    float* aggsA = wsf + AGGSA_OFF;
    float* aggvA = wsf + AGGVA_OFF;
    float* aggsB = wsf + AGGSB_OFF;
    float* aggvB = wsf + AGGVB_OFF;
    float* W2R = wsf + W2R_OFF;

    // L0: init state -> sA/vA, edge -> aggsA/aggvA; builds W2R for layers 1,2
    k_medge<0><<<512, 256, 0, stream>>>(pos, z, v, w_s_in, w_v_in,
                                        sws, swv, sA, vA, sA, vA,
                                        aggsB, aggvB,
                                        rw2, W2R, rb2, rw1, rb1,
                                        aggsA, aggvA);
    // L1: update(aggsA)+residual(sA) -> sB/vB, edge -> aggsB/aggvB
    k_medge<1><<<512, 256, 0, stream>>>(pos, z, v, w_s_in, w_v_in,
                                        sws, swv, sA, vA, sB, vB,
                                        aggsA, aggvA,
                                        rw2, W2R, rb2 + 1024, rw1 + 32, rb1 + 32,
                                        aggsB, aggvB);
    // L2: update(aggsB)+residual(sB) (no state write), edge -> aggsA/aggvA
    k_medge<2><<<512, 256, 0, stream>>>(pos, z, v, w_s_in, w_v_in,
                                        sws + 256, swv + 256, sB, vB, sA, vA,
                                        aggsB, aggvB,
                                        rw2, W2R, rb2 + 2048, rw1 + 64, rb1 + 64,
                                        aggsA, aggvA);
    // out: vec_L1 (vB) + L2 partials (aggvA)
    k_out<<<512, 256, 0, stream>>>(aggvA, swv + 512, wvo, vB, pos, out);
}